// Round 4
// baseline (1389.571 us; speedup 1.0000x reference)
//
#include <hip/hip_runtime.h>
#include <stdint.h>

typedef unsigned short u16;
typedef __bf16 bf16t;
typedef bf16t bf16x8 __attribute__((ext_vector_type(8)));
typedef float f32x4 __attribute__((ext_vector_type(4)));

#define NROWS 100000
#define DD 512
#define QD 128
#define KSEL 20000

// ---------- helpers ----------
__device__ __forceinline__ uint32_t fmono(float x){
  uint32_t u = __float_as_uint(x);
  return (u & 0x80000000u) ? ~u : (u | 0x80000000u);
}
__device__ __forceinline__ float fdemono(uint32_t k){
  uint32_t u = (k & 0x80000000u) ? (k & 0x7fffffffu) : ~k;
  return __uint_as_float(u);
}
__device__ __forceinline__ u16 f2bf(float x){  // RNE float->bf16 bits
  uint32_t u = __float_as_uint(x);
  u += 0x7fffu + ((u >> 16) & 1u);
  return (u16)(u >> 16);
}
__device__ __forceinline__ uint32_t pkbf(float a, float b){
  return (uint32_t)f2bf(a) | ((uint32_t)f2bf(b) << 16);
}

struct Scal {
  uint32_t sel_hi, cnt_before, keyT, gmk;
  float Z;
  uint32_t pad0, pad1, pad2;
  unsigned long long ck[2];   // argmax keys for c columns
};

#define MFMA16(A,B,C) __builtin_amdgcn_mfma_f32_16x16x32_bf16(A,B,C,0,0,0)

// ---------- small kernels (round-1 proven, verbatim) ----------
__global__ void k_conv(const float* __restrict__ Wl, const float* __restrict__ Wv,
                       const float* __restrict__ Wq, u16* __restrict__ wl_bf, u16* __restrict__ wvq_bf){
  int idx = blockIdx.x*256 + threadIdx.x;          // 589824 total
  if (idx < 262144) wl_bf[idx] = f2bf(Wl[idx]);
  int e = idx - 262144;
  if (e >= 0) wvq_bf[e] = f2bf(e < 262144 ? Wv[e] : Wq[e - 262144]);
}

__global__ void k_hist1(const float* __restrict__ preds, uint32_t* __restrict__ hist){
  int idx = blockIdx.x*256 + threadIdx.x;
  if (idx < NROWS) atomicAdd(&hist[fmono(preds[idx]) >> 16], 1u);
}

__global__ void k_sel1(const uint32_t* __restrict__ hist, Scal* sc){
  __shared__ uint32_t part[256];
  int t = threadIdx.x;
  uint32_t s = 0;
  for (int b = 0; b < 256; ++b) s += hist[t*256 + b];
  part[t] = s; __syncthreads();
  if (t == 0){
    uint32_t cum = 0;
    for (int p = 0; p < 256; ++p){
      if (cum + part[p] >= KSEL){
        uint32_t c2 = cum;
        for (int b = p*256; b < p*256 + 256; ++b){
          uint32_t hb = hist[b];
          if (c2 + hb >= KSEL){ sc->sel_hi = (uint32_t)b; sc->cnt_before = c2; break; }
          c2 += hb;
        }
        break;
      }
      cum += part[p];
    }
  }
}

__global__ void k_hist2(const float* __restrict__ preds, const Scal* sc, uint32_t* __restrict__ hist){
  int idx = blockIdx.x*256 + threadIdx.x;
  uint32_t sh = sc->sel_hi;
  if (idx < NROWS){
    uint32_t key = fmono(preds[idx]);
    if ((key >> 16) == sh) atomicAdd(&hist[key & 0xffffu], 1u);
  }
}

__global__ void k_sel2(const uint32_t* __restrict__ hist, Scal* sc){
  __shared__ uint32_t part[256];
  int t = threadIdx.x;
  uint32_t s = 0;
  for (int b = 0; b < 256; ++b) s += hist[t*256 + b];
  part[t] = s; __syncthreads();
  if (t == 0){
    uint32_t target = KSEL - sc->cnt_before;
    uint32_t cum = 0;
    for (int p = 0; p < 256; ++p){
      if (cum + part[p] >= target){
        uint32_t c2 = cum;
        for (int b = p*256; b < p*256 + 256; ++b){
          uint32_t hb = hist[b];
          if (c2 + hb >= target){ sc->keyT = (sc->sel_hi << 16) | (uint32_t)b; break; }
          c2 += hb;
        }
        break;
      }
      cum += part[p];
    }
  }
}

__global__ void k_gmax(const float* __restrict__ preds, Scal* sc){
  int idx = blockIdx.x*256 + threadIdx.x;
  uint32_t kT = sc->keyT;
  uint32_t km = 0;
  if (idx < NROWS){
    float p = preds[idx];
    float pm = (fmono(p) <= kT) ? 0.0f : p;
    km = fmono(pm);
  }
  #pragma unroll
  for (int off = 32; off; off >>= 1){ uint32_t o = __shfl_xor(km, off); km = km > o ? km : o; }
  if ((threadIdx.x & 63) == 0) atomicMax(&sc->gmk, km);
}

__global__ void k_sumexp(const float* __restrict__ preds, Scal* sc){
  int idx = blockIdx.x*256 + threadIdx.x;
  uint32_t kT = sc->keyT;
  float gm = fdemono(sc->gmk);
  float s = 0.f;
  if (idx < NROWS){
    float p = preds[idx];
    float pm = (fmono(p) <= kT) ? 0.0f : p;
    s = expf(pm - gm);
  }
  #pragma unroll
  for (int off = 32; off; off >>= 1) s += __shfl_xor(s, off);
  if ((threadIdx.x & 63) == 0) atomicAdd(&sc->Z, s);
}

__global__ void k_argc(const float* __restrict__ c, Scal* sc){
  int idx = blockIdx.x*256 + threadIdx.x;
  unsigned long long k0 = 0, k1 = 0;
  if (idx < NROWS){
    uint32_t inv = ~(uint32_t)idx;
    k0 = ((unsigned long long)fmono(c[(size_t)idx*2 + 0]) << 32) | inv;
    k1 = ((unsigned long long)fmono(c[(size_t)idx*2 + 1]) << 32) | inv;
  }
  #pragma unroll
  for (int off = 32; off; off >>= 1){
    unsigned long long o0 = __shfl_xor(k0, off); if (o0 > k0) k0 = o0;
    unsigned long long o1 = __shfl_xor(k1, off); if (o1 > k1) k1 = o1;
  }
  if ((threadIdx.x & 63) == 0){ atomicMax(&sc->ck[0], k0); atomicMax(&sc->ck[1], k1); }
}

// exact fp32 f rows at the two argmax indices
__global__ void k_mfeat(const float* __restrict__ feats, const float* __restrict__ preds,
                        const float* __restrict__ Wl, const float* __restrict__ bl,
                        const Scal* sc, float* __restrict__ fm){
  int j = blockIdx.x;
  int t = threadIdx.x;
  uint32_t m = ~(uint32_t)(sc->ck[j] & 0xffffffffull);
  float p = preds[m];
  float pm = (fmono(p) <= sc->keyT) ? 0.f : p;
  float g = 1.f + expf(pm - fdemono(sc->gmk)) / sc->Z;
  const float* fr = feats + (size_t)m * DD;
  for (int n = t; n < DD; n += 256){
    const float* wr = Wl + (size_t)n * DD;
    float acc = 0.f;
    for (int k = 0; k < DD; ++k) acc += fr[k] * wr[k];
    float v = bl[n] + g * acc;
    fm[j*DD + n] = v > 0.f ? v : 0.f;
  }
}

__global__ void k_qmax(const float* __restrict__ fm, const float* __restrict__ Wq,
                       const float* __restrict__ bq, float* __restrict__ qmv){
  int t = threadIdx.x;
  int j = t >> 7, q = t & 127;
  const float* fr = fm + j*DD;
  const float* wr = Wq + (size_t)q * DD;
  float acc = 0.f;
  for (int k = 0; k < DD; ++k) acc += fr[k] * wr[k];
  qmv[j*QD + q] = tanhf(bq[q] + acc);
}

// ---------- fused heavy kernel, M=64 ----------
// LDS (u16 units, total 29696 = 59392 B):
//  stage1: W1 [512][40] @0 (20480) ; A [64][40] @20480 (2560)
//  stage2: F  [64][264] @0 (16896) ; W2 [320][40] @16896 (12800) -> 29696
//  epilogue: Qf f32[64][128] @0 (u16 16384) ; qL f32[256] @16384 ; Ef f32[128] @16896
__launch_bounds__(256, 2)
__global__ void k_main64(const float* __restrict__ feats, const float* __restrict__ preds,
                         const u16* __restrict__ wl_bf, const u16* __restrict__ wvq_bf,
                         const float* __restrict__ bl, const float* __restrict__ bv,
                         const float* __restrict__ bq, const float* __restrict__ qmv,
                         const Scal* __restrict__ sc,
                         float* __restrict__ sumE, float* __restrict__ sumEV,
                         float* __restrict__ Aout){
  __shared__ __align__(16) u16 lds[29696];
  const int tid = threadIdx.x;
  const int wave = tid >> 6, lane = tid & 63, quad = lane >> 4, l16 = lane & 15;
  const long i0 = (long)blockIdx.x * 64;

  // ---- stage 1: f = relu(gX @ W1^T + b) ----
  const int mA = tid >> 2, kp = (tid & 3) * 8;
  long iA = i0 + mA; if (iA >= NROWS) iA = NROWS - 1;
  float gA;
  {
    float p = preds[iA];
    float pm = (fmono(p) <= sc->keyT) ? 0.f : p;
    gA = 1.f + expf(pm - fdemono(sc->gmk)) / sc->Z;
  }
  const float* ap = feats + iA*DD + kp;
  u16* Abase = &lds[20480];
  const u16* w0p = wl_bf + (size_t)tid*DD;
  const u16* w1p = wl_bf + (size_t)(tid+256)*DD;

  f32x4 acc1[4][8];
  #pragma unroll
  for (int r = 0; r < 4; ++r)
    #pragma unroll
    for (int j = 0; j < 8; ++j) acc1[r][j] = (f32x4){0.f,0.f,0.f,0.f};

  uint4 wr[8];
  float4 v0, v1;
  #pragma unroll
  for (int q = 0; q < 4; ++q){
    wr[q]   = ((const uint4*)w0p)[q];
    wr[4+q] = ((const uint4*)w1p)[q];
  }
  v0 = *(const float4*)(ap);
  v1 = *(const float4*)(ap + 4);

  for (int kc = 0; kc < 16; ++kc){
    __syncthreads();
    {
      uint4* d0 = (uint4*)&lds[tid*40];
      uint4* d1 = (uint4*)&lds[(tid+256)*40];
      d0[0]=wr[0]; d0[1]=wr[1]; d0[2]=wr[2]; d0[3]=wr[3];
      d1[0]=wr[4]; d1[1]=wr[5]; d1[2]=wr[6]; d1[3]=wr[7];
      uint4 pk;
      pk.x = pkbf(v0.x*gA, v0.y*gA); pk.y = pkbf(v0.z*gA, v0.w*gA);
      pk.z = pkbf(v1.x*gA, v1.y*gA); pk.w = pkbf(v1.z*gA, v1.w*gA);
      *(uint4*)&Abase[mA*40 + kp] = pk;
    }
    __syncthreads();
    if (kc < 15){
      #pragma unroll
      for (int q = 0; q < 4; ++q){
        wr[q]   = ((const uint4*)(w0p + (kc+1)*32))[q];
        wr[4+q] = ((const uint4*)(w1p + (kc+1)*32))[q];
      }
      v0 = *(const float4*)(ap + (kc+1)*32);
      v1 = *(const float4*)(ap + (kc+1)*32 + 4);
    }
    bf16x8 af0 = *(const bf16x8*)&Abase[(0*16 + l16)*40 + quad*8];
    bf16x8 af1 = *(const bf16x8*)&Abase[(1*16 + l16)*40 + quad*8];
    bf16x8 af2 = *(const bf16x8*)&Abase[(2*16 + l16)*40 + quad*8];
    bf16x8 af3 = *(const bf16x8*)&Abase[(3*16 + l16)*40 + quad*8];
    #pragma unroll
    for (int j = 0; j < 8; ++j){
      bf16x8 wf = *(const bf16x8*)&lds[(wave*128 + j*16 + l16)*40 + quad*8];
      acc1[0][j] = MFMA16(af0, wf, acc1[0][j]);
      acc1[1][j] = MFMA16(af1, wf, acc1[1][j]);
      acc1[2][j] = MFMA16(af2, wf, acc1[2][j]);
      acc1[3][j] = MFMA16(af3, wf, acc1[3][j]);
    }
  }

  // pack f (bias + relu) into registers: pk[r][j] holds rows (r*16+quad*4+0..3), col wave*128+j*16+l16
  uint2 pkF[4][8];
  #pragma unroll
  for (int j = 0; j < 8; ++j){
    float b = bl[wave*128 + j*16 + l16];
    #pragma unroll
    for (int r = 0; r < 4; ++r){
      float e0 = acc1[r][j][0] + b; e0 = e0 > 0.f ? e0 : 0.f;
      float e1 = acc1[r][j][1] + b; e1 = e1 > 0.f ? e1 : 0.f;
      float e2 = acc1[r][j][2] + b; e2 = e2 > 0.f ? e2 : 0.f;
      float e3 = acc1[r][j][3] + b; e3 = e3 > 0.f ? e3 : 0.f;
      pkF[r][j].x = pkbf(e0, e1);
      pkF[r][j].y = pkbf(e2, e3);
    }
  }

  // ---- stage 2: [V|Q] = f @ W2^T, K split into two halves of 256 ----
  f32x4 acc2[4][10];
  #pragma unroll
  for (int r = 0; r < 4; ++r)
    #pragma unroll
    for (int j = 0; j < 10; ++j) acc2[r][j] = (f32x4){0.f,0.f,0.f,0.f};

  u16* Fb = lds;             // [64][264]
  u16* W2b = &lds[16896];    // [320][40]

  for (int hk = 0; hk < 2; ++hk){
    __syncthreads();         // all previous LDS reads complete
    if ((wave >> 1) == hk){  // waves 0,1 own cols 0..255 ; waves 2,3 own 256..511
      int cl = (wave & 1)*128 + l16;
      #pragma unroll
      for (int j = 0; j < 8; ++j){
        int cc = cl + j*16;
        #pragma unroll
        for (int r = 0; r < 4; ++r){
          int row0 = r*16 + quad*4;
          Fb[(row0+0)*264 + cc] = (u16)(pkF[r][j].x);
          Fb[(row0+1)*264 + cc] = (u16)(pkF[r][j].x >> 16);
          Fb[(row0+2)*264 + cc] = (u16)(pkF[r][j].y);
          Fb[(row0+3)*264 + cc] = (u16)(pkF[r][j].y >> 16);
        }
      }
    }
    for (int h = 0; h < 2; ++h){
      for (int kc2 = 0; kc2 < 8; ++kc2){
        __syncthreads();     // F writes drained (first iter) / prior MFMA reads done
        for (int r = tid; r < 320; r += 256){
          const uint4* s = (const uint4*)(wvq_bf + (size_t)(h*320 + r)*DD + hk*256 + kc2*32);
          uint4* d = (uint4*)&W2b[r*40];
          d[0]=s[0]; d[1]=s[1]; d[2]=s[2]; d[3]=s[3];
        }
        __syncthreads();
        bf16x8 af0 = *(const bf16x8*)&Fb[(0*16 + l16)*264 + kc2*32 + quad*8];
        bf16x8 af1 = *(const bf16x8*)&Fb[(1*16 + l16)*264 + kc2*32 + quad*8];
        bf16x8 af2 = *(const bf16x8*)&Fb[(2*16 + l16)*264 + kc2*32 + quad*8];
        bf16x8 af3 = *(const bf16x8*)&Fb[(3*16 + l16)*264 + kc2*32 + quad*8];
        #pragma unroll
        for (int jj = 0; jj < 5; ++jj){
          bf16x8 wf = *(const bf16x8*)&W2b[(wave*80 + jj*16 + l16)*40 + quad*8];
          acc2[0][h*5+jj] = MFMA16(af0, wf, acc2[0][h*5+jj]);
          acc2[1][h*5+jj] = MFMA16(af1, wf, acc2[1][h*5+jj]);
          acc2[2][h*5+jj] = MFMA16(af2, wf, acc2[2][h*5+jj]);
          acc2[3][h*5+jj] = MFMA16(af3, wf, acc2[3][h*5+jj]);
        }
      }
    }
  }
  __syncthreads();           // stage-2 LDS reads done; overlay epilogue buffers

  float* Qf = (float*)lds;          // [64][128]
  float* qL = (float*)&lds[16384];  // 256 floats
  float* Ef = (float*)&lds[16896];  // 128 floats

  // epilogue 1: qmv preload; Q -> tanh -> Qf ; V bias into acc2
  qL[tid] = qmv[tid];
  #pragma unroll
  for (int t2 = 0; t2 < 10; ++t2){
    int h = t2 >= 5 ? 1 : 0;
    int col = h*320 + wave*80 + (t2 - h*5)*16 + l16;
    if (col >= 512){
      int qc = col - 512;
      float bqv = bq[qc];
      #pragma unroll
      for (int r = 0; r < 4; ++r)
        #pragma unroll
        for (int e = 0; e < 4; ++e){
          int row = r*16 + quad*4 + e;
          Qf[row*QD + qc] = tanhf(acc2[r][t2][e] + bqv);
        }
    } else {
      float bvv = bv[col];
      #pragma unroll
      for (int r = 0; r < 4; ++r)
        #pragma unroll
        for (int e = 0; e < 4; ++e) acc2[r][t2][e] += bvv;
    }
  }
  __syncthreads();

  // epilogue 2: scores + exp (unnormalized A)
  {
    int row = tid >> 2, j = (tid >> 1) & 1, half = tid & 1;
    const float4* Ql = (const float4*)(Qf + row*QD + half*64);
    const float4* qv = (const float4*)(qL + j*QD + half*64);
    float s = 0.f;
    #pragma unroll
    for (int k = 0; k < 16; ++k){
      float4 x = Ql[k], w = qv[k];
      s += x.x*w.x + x.y*w.y + x.z*w.z + x.w*w.w;
    }
    s += __shfl_xor(s, 1);
    if (half == 0){
      bool valid = (i0 + row) < NROWS;
      float e = valid ? expf(s * 0.08838834764831845f) : 0.f;
      Ef[row*2 + j] = e;
      if (valid) Aout[(i0 + row)*2 + j] = e;
    }
  }
  __syncthreads();

  if (tid < 2){
    float ss = 0.f;
    for (int r = 0; r < 64; ++r) ss += Ef[r*2 + tid];
    atomicAdd(&sumE[tid], ss);
  }

  // epilogue 3: B partials
  float er0[4][4], er1[4][4];
  #pragma unroll
  for (int r = 0; r < 4; ++r)
    #pragma unroll
    for (int e = 0; e < 4; ++e){
      int row = r*16 + quad*4 + e;
      er0[r][e] = Ef[row*2 + 0];
      er1[r][e] = Ef[row*2 + 1];
    }
  #pragma unroll
  for (int t2 = 0; t2 < 10; ++t2){
    int h = t2 >= 5 ? 1 : 0;
    int col = h*320 + wave*80 + (t2 - h*5)*16 + l16;
    if (col < 512){
      float b0 = 0.f, b1 = 0.f;
      #pragma unroll
      for (int r = 0; r < 4; ++r)
        #pragma unroll
        for (int e = 0; e < 4; ++e){
          float v = acc2[r][t2][e];
          b0 += v * er0[r][e];
          b1 += v * er1[r][e];
        }
      b0 += __shfl_xor(b0, 16); b0 += __shfl_xor(b0, 32);
      b1 += __shfl_xor(b1, 16); b1 += __shfl_xor(b1, 32);
      if (quad == 0){
        atomicAdd(&sumEV[col], b0);
        atomicAdd(&sumEV[512 + col], b1);
      }
    }
  }
}

__global__ void k_norm(float* __restrict__ Aout, const float* __restrict__ sumE){
  int idx = blockIdx.x*256 + threadIdx.x;
  if (idx < 200000) Aout[idx] = Aout[idx] / sumE[idx & 1];
}

__global__ void k_final(const float* __restrict__ sumEV, const float* __restrict__ sumE,
                        const float* __restrict__ Wfcc, const float* __restrict__ bfcc,
                        float* __restrict__ out){
  __shared__ float red[512];
  int t = threadIdx.x;
  float z0 = sumE[0], z1 = sumE[1];
  float c0 = 0.f, c1 = 0.f;
  for (int e = t; e < 1024; e += 256){
    float bvv = sumEV[e] / ((e >> 9) ? z1 : z0);
    out[200002 + e] = bvv;
    c0 += bvv * Wfcc[e];
    c1 += bvv * Wfcc[1024 + e];
  }
  red[t] = c0; red[256 + t] = c1;
  __syncthreads();
  for (int s = 128; s; s >>= 1){
    if (t < s){ red[t] += red[t + s]; red[256 + t] += red[256 + t + s]; }
    __syncthreads();
  }
  if (t == 0){ out[0] = red[0] + bfcc[0]; out[1] = red[256] + bfcc[1]; }
}

// ---------- launch ----------
extern "C" void kernel_launch(void* const* d_in, const int* in_sizes, int n_in,
                              void* d_out, int out_size, void* d_ws, size_t ws_size,
                              hipStream_t stream){
  (void)in_sizes; (void)n_in; (void)out_size; (void)ws_size;
  const float* feats = (const float*)d_in[0];
  const float* c     = (const float*)d_in[1];
  const float* preds = (const float*)d_in[2];
  const float* W_lin = (const float*)d_in[3];
  const float* b_lin = (const float*)d_in[4];
  const float* W_q   = (const float*)d_in[5];
  const float* b_q   = (const float*)d_in[6];
  const float* W_v   = (const float*)d_in[7];
  const float* b_v   = (const float*)d_in[8];
  const float* W_fcc = (const float*)d_in[9];
  const float* b_fcc = (const float*)d_in[10];
  float* out = (float*)d_out;
  char* ws = (char*)d_ws;

  // ws layout (bytes) — round-1 proven
  u16*      wl_bf  = (u16*)(ws + 0);            // 524288
  u16*      wvq_bf = (u16*)(ws + 524288);       // 655360  -> 1179648
  uint32_t* hist1  = (uint32_t*)(ws + 1179648); // 262144  -> 1441792
  uint32_t* hist2  = (uint32_t*)(ws + 1441792); // 262144  -> 1703936
  Scal*     sc     = (Scal*)(ws + 1703936);     // 48 (pad to 64)
  float*    fm     = (float*)(ws + 1704000);    // 4096 -> 1708096
  float*    qmv    = (float*)(ws + 1708096);    // 1024 -> 1709120
  float*    sumE   = (float*)(ws + 1709120);    // 8
  float*    sumEV  = (float*)(ws + 1709136);    // 4096 -> 1713232

  hipMemsetAsync(ws + 1179648, 0, 1713232 - 1179648, stream);

  k_conv  <<<2304, 256, 0, stream>>>(W_lin, W_v, W_q, wl_bf, wvq_bf);
  k_hist1 <<<391, 256, 0, stream>>>(preds, hist1);
  k_sel1  <<<1, 256, 0, stream>>>(hist1, sc);
  k_hist2 <<<391, 256, 0, stream>>>(preds, sc, hist2);
  k_sel2  <<<1, 256, 0, stream>>>(hist2, sc);
  k_gmax  <<<391, 256, 0, stream>>>(preds, sc);
  k_sumexp<<<391, 256, 0, stream>>>(preds, sc);
  k_argc  <<<391, 256, 0, stream>>>(c, sc);
  k_mfeat <<<2, 256, 0, stream>>>(feats, preds, W_lin, b_lin, sc, fm);
  k_qmax  <<<1, 256, 0, stream>>>(fm, W_q, b_q, qmv);
  k_main64<<<1563, 256, 0, stream>>>(feats, preds, wl_bf, wvq_bf, b_lin, b_v, b_q,
                                     qmv, sc, sumE, sumEV, out + 2);
  k_norm  <<<782, 256, 0, stream>>>(out + 2, sumE);
  k_final <<<1, 256, 0, stream>>>(sumEV, sumE, W_fcc, b_fcc, out);
}

// Round 5
// 1310.534 us; speedup vs baseline: 1.0603x; 1.0603x over previous
//
#include <hip/hip_runtime.h>
#include <stdint.h>

typedef unsigned short u16;
typedef __bf16 bf16t;
typedef bf16t bf16x8 __attribute__((ext_vector_type(8)));
typedef float f32x4 __attribute__((ext_vector_type(4)));

#define NROWS 100000
#define MPAD 100096
#define DD 512
#define QD 128
#define KSEL 20000

// ---------- helpers ----------
__device__ __forceinline__ uint32_t fmono(float x){
  uint32_t u = __float_as_uint(x);
  return (u & 0x80000000u) ? ~u : (u | 0x80000000u);
}
__device__ __forceinline__ u16 f2bf(float x){  // RNE float->bf16 bits
  uint32_t u = __float_as_uint(x);
  u += 0x7fffu + ((u >> 16) & 1u);
  return (u16)(u >> 16);
}
__device__ __forceinline__ uint32_t pkbf(float a, float b){
  return (uint32_t)f2bf(a) | ((uint32_t)f2bf(b) << 16);
}

struct Scal {
  uint32_t sel_hi, cnt_before, keyT, gmk;
  float Z;
  uint32_t pad0, pad1, pad2;
  unsigned long long ck[2];   // argmax keys for c columns
};

#define MFMA16(A,B,C) __builtin_amdgcn_mfma_f32_16x16x32_bf16(A,B,C,0,0,0)

// ---------- small kernels ----------
__global__ void k_conv(const float* __restrict__ Wl, const float* __restrict__ Wv,
                       const float* __restrict__ Wq, u16* __restrict__ wl_bf, u16* __restrict__ wvq_bf){
  int idx = blockIdx.x*256 + threadIdx.x;          // 589824 total
  if (idx < 262144) wl_bf[idx] = f2bf(Wl[idx]);
  int e = idx - 262144;
  if (e >= 0) wvq_bf[e] = f2bf(e < 262144 ? Wv[e] : Wq[e - 262144]);
}

__global__ void k_hist1(const float* __restrict__ preds, uint32_t* __restrict__ hist){
  int idx = blockIdx.x*256 + threadIdx.x;
  if (idx < NROWS) atomicAdd(&hist[fmono(preds[idx]) >> 16], 1u);
}

// same semantics as round-1 k_sel1, but the 256-iteration serial scan reads LDS not global
__global__ void k_sel1(const uint32_t* __restrict__ hist, Scal* sc){
  __shared__ uint32_t part[256], binv[256];
  __shared__ uint32_t sp, sbase;
  int t = threadIdx.x;
  uint32_t s = 0;
  const uint4* h4 = (const uint4*)(hist + t*256);
  #pragma unroll 8
  for (int i = 0; i < 64; ++i){ uint4 v = h4[i]; s += v.x + v.y + v.z + v.w; }
  part[t] = s; __syncthreads();
  if (t == 0){
    uint32_t cum = 0;
    for (int p = 0; p < 256; ++p){
      if (cum + part[p] >= KSEL){ sp = (uint32_t)p; sbase = cum; break; }
      cum += part[p];
    }
  }
  __syncthreads();
  binv[t] = hist[sp*256 + t];
  __syncthreads();
  if (t == 0){
    uint32_t c2 = sbase, p = sp;
    for (int b = 0; b < 256; ++b){
      uint32_t hb = binv[b];
      if (c2 + hb >= KSEL){ sc->sel_hi = p*256 + (uint32_t)b; sc->cnt_before = c2; break; }
      c2 += hb;
    }
  }
}

__global__ void k_hist2(const float* __restrict__ preds, const Scal* sc, uint32_t* __restrict__ hist){
  int idx = blockIdx.x*256 + threadIdx.x;
  uint32_t sh = sc->sel_hi;
  if (idx < NROWS){
    uint32_t key = fmono(preds[idx]);
    if ((key >> 16) == sh) atomicAdd(&hist[key & 0xffffu], 1u);
  }
}

__global__ void k_sel2(const uint32_t* __restrict__ hist, Scal* sc){
  __shared__ uint32_t part[256], binv[256];
  __shared__ uint32_t sp, sbase;
  int t = threadIdx.x;
  uint32_t target = KSEL - sc->cnt_before;
  uint32_t s = 0;
  const uint4* h4 = (const uint4*)(hist + t*256);
  #pragma unroll 8
  for (int i = 0; i < 64; ++i){ uint4 v = h4[i]; s += v.x + v.y + v.z + v.w; }
  part[t] = s; __syncthreads();
  if (t == 0){
    uint32_t cum = 0;
    for (int p = 0; p < 256; ++p){
      if (cum + part[p] >= target){ sp = (uint32_t)p; sbase = cum; break; }
      cum += part[p];
    }
  }
  __syncthreads();
  binv[t] = hist[sp*256 + t];
  __syncthreads();
  if (t == 0){
    uint32_t c2 = sbase, p = sp;
    for (int b = 0; b < 256; ++b){
      uint32_t hb = binv[b];
      if (c2 + hb >= target){ sc->keyT = (sc->sel_hi << 16) | (p*256 + (uint32_t)b); break; }
      c2 += hb;
    }
  }
}

// Z = sum(exp(pm)) with no max-subtraction (|preds| <= ~5, exp <= ~150: safe)
__global__ void k_sumexp(const float* __restrict__ preds, Scal* sc){
  int idx = blockIdx.x*256 + threadIdx.x;
  uint32_t kT = sc->keyT;
  float s = 0.f;
  if (idx < NROWS){
    float p = preds[idx];
    float pm = (fmono(p) <= kT) ? 0.0f : p;
    s = __expf(pm);
  }
  #pragma unroll
  for (int off = 32; off; off >>= 1) s += __shfl_xor(s, off);
  if ((threadIdx.x & 63) == 0) atomicAdd(&sc->Z, s);
}

__global__ void k_argc(const float* __restrict__ c, Scal* sc){
  int idx = blockIdx.x*256 + threadIdx.x;
  unsigned long long k0 = 0, k1 = 0;
  if (idx < NROWS){
    uint32_t inv = ~(uint32_t)idx;
    k0 = ((unsigned long long)fmono(c[(size_t)idx*2 + 0]) << 32) | inv;
    k1 = ((unsigned long long)fmono(c[(size_t)idx*2 + 1]) << 32) | inv;
  }
  #pragma unroll
  for (int off = 32; off; off >>= 1){
    unsigned long long o0 = __shfl_xor(k0, off); if (o0 > k0) k0 = o0;
    unsigned long long o1 = __shfl_xor(k1, off); if (o1 > k1) k1 = o1;
  }
  if ((threadIdx.x & 63) == 0){ atomicMax(&sc->ck[0], k0); atomicMax(&sc->ck[1], k1); }
}

// exact fp32 f rows at the two argmax indices (float4 vectorized)
__global__ void k_mfeat(const float* __restrict__ feats, const float* __restrict__ preds,
                        const float* __restrict__ Wl, const float* __restrict__ bl,
                        const Scal* sc, float* __restrict__ fm){
  int j = blockIdx.x;
  int t = threadIdx.x;
  uint32_t m = ~(uint32_t)(sc->ck[j] & 0xffffffffull);
  float p = preds[m];
  float pm = (fmono(p) <= sc->keyT) ? 0.f : p;
  float g = 1.f + __expf(pm) / sc->Z;
  const float4* fr = (const float4*)(feats + (size_t)m * DD);
  for (int n = t; n < DD; n += 256){
    const float4* wr = (const float4*)(Wl + (size_t)n * DD);
    float a0 = 0.f, a1 = 0.f, a2 = 0.f, a3 = 0.f;
    #pragma unroll 4
    for (int k = 0; k < 128; k += 4){
      float4 x0 = fr[k],   w0 = wr[k];   a0 += x0.x*w0.x + x0.y*w0.y + x0.z*w0.z + x0.w*w0.w;
      float4 x1 = fr[k+1], w1 = wr[k+1]; a1 += x1.x*w1.x + x1.y*w1.y + x1.z*w1.z + x1.w*w1.w;
      float4 x2 = fr[k+2], w2 = wr[k+2]; a2 += x2.x*w2.x + x2.y*w2.y + x2.z*w2.z + x2.w*w2.w;
      float4 x3 = fr[k+3], w3 = wr[k+3]; a3 += x3.x*w3.x + x3.y*w3.y + x3.z*w3.z + x3.w*w3.w;
    }
    float v = bl[n] + g * ((a0 + a1) + (a2 + a3));
    fm[j*DD + n] = v > 0.f ? v : 0.f;
  }
}

__global__ void k_qmax(const float* __restrict__ fm, const float* __restrict__ Wq,
                       const float* __restrict__ bq, float* __restrict__ qmv){
  int t = threadIdx.x;
  int j = t >> 7, q = t & 127;
  const float4* fr = (const float4*)(fm + j*DD);
  const float4* wr = (const float4*)(Wq + (size_t)q * DD);
  float a0 = 0.f, a1 = 0.f, a2 = 0.f, a3 = 0.f;
  #pragma unroll 4
  for (int k = 0; k < 128; k += 4){
    float4 x0 = fr[k],   w0 = wr[k];   a0 += x0.x*w0.x + x0.y*w0.y + x0.z*w0.z + x0.w*w0.w;
    float4 x1 = fr[k+1], w1 = wr[k+1]; a1 += x1.x*w1.x + x1.y*w1.y + x1.z*w1.z + x1.w*w1.w;
    float4 x2 = fr[k+2], w2 = wr[k+2]; a2 += x2.x*w2.x + x2.y*w2.y + x2.z*w2.z + x2.w*w2.w;
    float4 x3 = fr[k+3], w3 = wr[k+3]; a3 += x3.x*w3.x + x3.y*w3.y + x3.z*w3.z + x3.w*w3.w;
  }
  qmv[j*QD + q] = tanhf(bq[q] + (a0 + a1) + (a2 + a3));
}

// ---------- k_scale: gx = bf16((1 + softmax(preds)) * feats) ----------
__global__ void k_scale(const float* __restrict__ feats, const float* __restrict__ preds,
                        const Scal* __restrict__ sc, u16* __restrict__ gx){
  int idx = blockIdx.x*256 + threadIdx.x;     // 6.4M = 100000*64 exactly
  int row = idx >> 6, cpos = (idx & 63) * 8;
  float p = preds[row];
  float pm = (fmono(p) <= sc->keyT) ? 0.f : p;
  float g = 1.f + __expf(pm) / sc->Z;
  const float4* s = (const float4*)(feats + (size_t)row*DD + cpos);
  float4 v0 = s[0], v1 = s[1];
  uint4 pk;
  pk.x = pkbf(v0.x*g, v0.y*g); pk.y = pkbf(v0.z*g, v0.w*g);
  pk.z = pkbf(v1.x*g, v1.y*g); pk.w = pkbf(v1.z*g, v1.w*g);
  *(uint4*)(gx + (size_t)row*DD + cpos) = pk;
}

// ---------- shared 128x128x512 bf16 GEMM core ----------
// LDS u16[20480]: A tiles [2][128][40] @0 ; B tiles [2][128][40] @10240
// acc[mi][ni][e]: row = wm*64 + mi*16 + quad*4 + e ; col = wn*64 + ni*16 + l16
__device__ __forceinline__ void gemm_core(const u16* __restrict__ Ab, const u16* __restrict__ Bb,
                                          u16* lds, f32x4 (&acc)[4][4], int tid){
  const int row_s = tid >> 1, kh = tid & 1;
  const int lane = tid & 63, quad = lane >> 4, l16 = lane & 15;
  const int wave = tid >> 6, wm = wave >> 1, wn = wave & 1;
  const u16* aS = Ab + (size_t)row_s*DD + kh*32;
  const u16* bS = Bb + (size_t)row_s*DD + kh*32;
  u16* aL = lds + kh*5120 + row_s*40;
  u16* bL = lds + 10240 + kh*5120 + row_s*40;
  uint4 ar[4], br[4];
  #pragma unroll
  for (int q = 0; q < 4; ++q){
    ar[q] = *(const uint4*)(aS + q*8);
    br[q] = *(const uint4*)(bS + q*8);
  }
  for (int ks = 0; ks < 8; ++ks){
    __syncthreads();
    #pragma unroll
    for (int q = 0; q < 4; ++q){
      *(uint4*)(aL + q*8) = ar[q];
      *(uint4*)(bL + q*8) = br[q];
    }
    __syncthreads();
    if (ks < 7){
      #pragma unroll
      for (int q = 0; q < 4; ++q){
        ar[q] = *(const uint4*)(aS + (ks+1)*64 + q*8);
        br[q] = *(const uint4*)(bS + (ks+1)*64 + q*8);
      }
    }
    #pragma unroll
    for (int kc2 = 0; kc2 < 2; ++kc2){
      bf16x8 af[4], bf[4];
      #pragma unroll
      for (int mi = 0; mi < 4; ++mi)
        af[mi] = *(const bf16x8*)&lds[kc2*5120 + (wm*64 + mi*16 + l16)*40 + quad*8];
      #pragma unroll
      for (int ni = 0; ni < 4; ++ni)
        bf[ni] = *(const bf16x8*)&lds[10240 + kc2*5120 + (wn*64 + ni*16 + l16)*40 + quad*8];
      #pragma unroll
      for (int mi = 0; mi < 4; ++mi)
        #pragma unroll
        for (int ni = 0; ni < 4; ++ni)
          acc[mi][ni] = MFMA16(af[mi], bf[ni], acc[mi][ni]);
    }
  }
}

// ---------- k_f: f = relu(gx @ Wl^T + bl) -> bf16 ----------
__launch_bounds__(256, 2)
__global__ void k_f(const u16* __restrict__ gx, const u16* __restrict__ wl,
                    const float* __restrict__ bl, u16* __restrict__ fout){
  __shared__ __align__(16) u16 lds[20480];
  const int tid = threadIdx.x;
  const int lane = tid & 63, quad = lane >> 4, l16 = lane & 15;
  const int wave = tid >> 6, wm = wave >> 1, wn = wave & 1;
  const long i0 = (long)(blockIdx.x >> 2) * 128;
  const int n0 = (blockIdx.x & 3) * 128;

  f32x4 acc[4][4];
  #pragma unroll
  for (int mi = 0; mi < 4; ++mi)
    #pragma unroll
    for (int ni = 0; ni < 4; ++ni) acc[mi][ni] = (f32x4){0.f,0.f,0.f,0.f};
  gemm_core(gx + (size_t)i0*DD, wl + (size_t)n0*DD, lds, acc, tid);

  float blv[4];
  #pragma unroll
  for (int ni = 0; ni < 4; ++ni) blv[ni] = bl[n0 + wn*64 + ni*16 + l16];

  #pragma unroll
  for (int half = 0; half < 2; ++half){
    __syncthreads();
    if (wm == half){
      #pragma unroll
      for (int mi = 0; mi < 4; ++mi)
        #pragma unroll
        for (int ni = 0; ni < 4; ++ni){
          int col = wn*64 + ni*16 + l16;
          #pragma unroll
          for (int e = 0; e < 4; ++e){
            int lrow = mi*16 + quad*4 + e;
            float v = acc[mi][ni][e] + blv[ni];
            lds[lrow*136 + col] = f2bf(v > 0.f ? v : 0.f);
          }
        }
    }
    __syncthreads();
    #pragma unroll
    for (int i = 0; i < 4; ++i){
      int ch = i*256 + tid;
      int lrow = ch >> 4, cs = ch & 15;
      *(uint4*)(fout + (i0 + half*64 + lrow)*DD + n0 + cs*8) = *(const uint4*)&lds[lrow*136 + cs*8];
    }
  }
}

// ---------- k_q: Q = tanh(f @ Wq^T + bq); scores, e = exp(score/sqrt(128)) ----------
__launch_bounds__(256, 2)
__global__ void k_q(const u16* __restrict__ f, const u16* __restrict__ wvq,
                    const float* __restrict__ bq, const float* __restrict__ qmv,
                    float* __restrict__ ews, float* __restrict__ sumE,
                    float* __restrict__ Aout){
  __shared__ __align__(16) u16 lds[20480];
  const int tid = threadIdx.x;
  const int lane = tid & 63, quad = lane >> 4, l16 = lane & 15;
  const int wave = tid >> 6, wm = wave >> 1, wn = wave & 1;
  const long i0 = (long)blockIdx.x * 128;

  f32x4 acc[4][4];
  #pragma unroll
  for (int mi = 0; mi < 4; ++mi)
    #pragma unroll
    for (int ni = 0; ni < 4; ++ni) acc[mi][ni] = (f32x4){0.f,0.f,0.f,0.f};
  gemm_core(f + (size_t)i0*DD, wvq + (size_t)512*DD, lds, acc, tid);

  float qv0[4], qv1[4], bqv[4];
  #pragma unroll
  for (int ni = 0; ni < 4; ++ni){
    int qc = wn*64 + ni*16 + l16;
    qv0[ni] = qmv[qc]; qv1[ni] = qmv[QD + qc]; bqv[ni] = bq[qc];
  }
  float p[4][4][2];
  #pragma unroll
  for (int mi = 0; mi < 4; ++mi)
    #pragma unroll
    for (int e = 0; e < 4; ++e){ p[mi][e][0] = 0.f; p[mi][e][1] = 0.f; }
  #pragma unroll
  for (int mi = 0; mi < 4; ++mi)
    #pragma unroll
    for (int ni = 0; ni < 4; ++ni)
      #pragma unroll
      for (int e = 0; e < 4; ++e){
        float t = tanhf(acc[mi][ni][e] + bqv[ni]);
        p[mi][e][0] += t * qv0[ni];
        p[mi][e][1] += t * qv1[ni];
      }
  #pragma unroll
  for (int off = 1; off <= 8; off <<= 1)
    #pragma unroll
    for (int mi = 0; mi < 4; ++mi)
      #pragma unroll
      for (int e = 0; e < 4; ++e){
        p[mi][e][0] += __shfl_xor(p[mi][e][0], off);
        p[mi][e][1] += __shfl_xor(p[mi][e][1], off);
      }
  __syncthreads();  // gemm LDS reads done; overlay sred
  float* sred = (float*)lds;  // [128][2 j][2 wn]
  if (l16 == 0){
    #pragma unroll
    for (int mi = 0; mi < 4; ++mi)
      #pragma unroll
      for (int e = 0; e < 4; ++e){
        int row = wm*64 + mi*16 + quad*4 + e;
        sred[row*4 + 0 + wn] = p[mi][e][0];
        sred[row*4 + 2 + wn] = p[mi][e][1];
      }
  }
  __syncthreads();
  int row = tid >> 1, j = tid & 1;
  float s = (sred[row*4 + j*2 + 0] + sred[row*4 + j*2 + 1]) * 0.08838834764831845f;
  bool valid = (i0 + row) < NROWS;
  float ev = valid ? __expf(s) : 0.f;
  ews[(i0 + row)*2 + j] = ev;
  if (valid) Aout[(i0 + row)*2 + j] = ev;
  float t2 = ev;
  #pragma unroll
  for (int off = 2; off <= 32; off <<= 1) t2 += __shfl_xor(t2, off);
  if (lane < 2) atomicAdd(&sumE[j], t2);
}

// ---------- k_v: V = f @ Wv^T + bv; B partials via e ----------
__launch_bounds__(256, 2)
__global__ void k_v(const u16* __restrict__ f, const u16* __restrict__ wvq,
                    const float* __restrict__ bv, const float* __restrict__ ews,
                    float* __restrict__ sumEV){
  __shared__ __align__(16) u16 lds[20480];
  const int tid = threadIdx.x;
  const int lane = tid & 63, quad = lane >> 4, l16 = lane & 15;
  const int wave = tid >> 6, wm = wave >> 1, wn = wave & 1;
  const long i0 = (long)(blockIdx.x >> 2) * 128;
  const int n0 = (blockIdx.x & 3) * 128;

  f32x4 acc[4][4];
  #pragma unroll
  for (int mi = 0; mi < 4; ++mi)
    #pragma unroll
    for (int ni = 0; ni < 4; ++ni) acc[mi][ni] = (f32x4){0.f,0.f,0.f,0.f};
  gemm_core(f + (size_t)i0*DD, wvq + (size_t)n0*DD, lds, acc, tid);

  float bvv[4];
  #pragma unroll
  for (int ni = 0; ni < 4; ++ni) bvv[ni] = bv[n0 + wn*64 + ni*16 + l16];
  float e0[4][4], e1[4][4];
  #pragma unroll
  for (int mi = 0; mi < 4; ++mi)
    #pragma unroll
    for (int e = 0; e < 4; ++e){
      long r = i0 + wm*64 + mi*16 + quad*4 + e;
      e0[mi][e] = ews[r*2 + 0];
      e1[mi][e] = ews[r*2 + 1];
    }
  float b0[4] = {0.f,0.f,0.f,0.f}, b1[4] = {0.f,0.f,0.f,0.f};
  #pragma unroll
  for (int mi = 0; mi < 4; ++mi)
    #pragma unroll
    for (int ni = 0; ni < 4; ++ni)
      #pragma unroll
      for (int e = 0; e < 4; ++e){
        float v = acc[mi][ni][e] + bvv[ni];
        b0[ni] += v * e0[mi][e];
        b1[ni] += v * e1[mi][e];
      }
  #pragma unroll
  for (int ni = 0; ni < 4; ++ni){
    b0[ni] += __shfl_xor(b0[ni], 16); b0[ni] += __shfl_xor(b0[ni], 32);
    b1[ni] += __shfl_xor(b1[ni], 16); b1[ni] += __shfl_xor(b1[ni], 32);
  }
  if (quad == 0){
    #pragma unroll
    for (int ni = 0; ni < 4; ++ni){
      int col = n0 + wn*64 + ni*16 + l16;
      atomicAdd(&sumEV[col], b0[ni]);
      atomicAdd(&sumEV[512 + col], b1[ni]);
    }
  }
}

// ---------- fallback fused kernel (round-4, passing) ----------
__launch_bounds__(256, 2)
__global__ void k_main64(const float* __restrict__ feats, const float* __restrict__ preds,
                         const u16* __restrict__ wl_bf, const u16* __restrict__ wvq_bf,
                         const float* __restrict__ bl, const float* __restrict__ bv,
                         const float* __restrict__ bq, const float* __restrict__ qmv,
                         const Scal* __restrict__ sc,
                         float* __restrict__ sumE, float* __restrict__ sumEV,
                         float* __restrict__ Aout){
  __shared__ __align__(16) u16 lds[29696];
  const int tid = threadIdx.x;
  const int wave = tid >> 6, lane = tid & 63, quad = lane >> 4, l16 = lane & 15;
  const long i0 = (long)blockIdx.x * 64;

  const int mA = tid >> 2, kp = (tid & 3) * 8;
  long iA = i0 + mA; if (iA >= NROWS) iA = NROWS - 1;
  float gA;
  {
    float p = preds[iA];
    float pm = (fmono(p) <= sc->keyT) ? 0.f : p;
    gA = 1.f + __expf(pm) / sc->Z;
  }
  const float* ap = feats + iA*DD + kp;
  u16* Abase = &lds[20480];
  const u16* w0p = wl_bf + (size_t)tid*DD;
  const u16* w1p = wl_bf + (size_t)(tid+256)*DD;

  f32x4 acc1[4][8];
  #pragma unroll
  for (int r = 0; r < 4; ++r)
    #pragma unroll
    for (int j = 0; j < 8; ++j) acc1[r][j] = (f32x4){0.f,0.f,0.f,0.f};

  uint4 wr[8];
  float4 v0, v1;
  #pragma unroll
  for (int q = 0; q < 4; ++q){
    wr[q]   = ((const uint4*)w0p)[q];
    wr[4+q] = ((const uint4*)w1p)[q];
  }
  v0 = *(const float4*)(ap);
  v1 = *(const float4*)(ap + 4);

  for (int kc = 0; kc < 16; ++kc){
    __syncthreads();
    {
      uint4* d0 = (uint4*)&lds[tid*40];
      uint4* d1 = (uint4*)&lds[(tid+256)*40];
      d0[0]=wr[0]; d0[1]=wr[1]; d0[2]=wr[2]; d0[3]=wr[3];
      d1[0]=wr[4]; d1[1]=wr[5]; d1[2]=wr[6]; d1[3]=wr[7];
      uint4 pk;
      pk.x = pkbf(v0.x*gA, v0.y*gA); pk.y = pkbf(v0.z*gA, v0.w*gA);
      pk.z = pkbf(v1.x*gA, v1.y*gA); pk.w = pkbf(v1.z*gA, v1.w*gA);
      *(uint4*)&Abase[mA*40 + kp] = pk;
    }
    __syncthreads();
    if (kc < 15){
      #pragma unroll
      for (int q = 0; q < 4; ++q){
        wr[q]   = ((const uint4*)(w0p + (kc+1)*32))[q];
        wr[4+q] = ((const uint4*)(w1p + (kc+1)*32))[q];
      }
      v0 = *(const float4*)(ap + (kc+1)*32);
      v1 = *(const float4*)(ap + (kc+1)*32 + 4);
    }
    bf16x8 af0 = *(const bf16x8*)&Abase[(0*16 + l16)*40 + quad*8];
    bf16x8 af1 = *(const bf16x8*)&Abase[(1*16 + l16)*40 + quad*8];
    bf16x8 af2 = *(const bf16x8*)&Abase[(2*16 + l16)*40 + quad*8];
    bf16x8 af3 = *(const bf16x8*)&Abase[(3*16 + l16)*40 + quad*8];
    #pragma unroll
    for (int j = 0; j < 8; ++j){
      bf16x8 wf = *(const bf16x8*)&lds[(wave*128 + j*16 + l16)*40 + quad*8];
      acc1[0][j] = MFMA16(af0, wf, acc1[0][j]);
      acc1[1][j] = MFMA16(af1, wf, acc1[1][j]);
      acc1[2][j] = MFMA16(af2, wf, acc1[2][j]);
      acc1[3][j] = MFMA16(af3, wf, acc1[3][j]);
    }
  }

  uint2 pkF[4][8];
  #pragma unroll
  for (int j = 0; j < 8; ++j){
    float b = bl[wave*128 + j*16 + l16];
    #pragma unroll
    for (int r = 0; r < 4; ++r){
      float e0 = acc1[r][j][0] + b; e0 = e0 > 0.f ? e0 : 0.f;
      float e1 = acc1[r][j][1] + b; e1 = e1 > 0.f ? e1 : 0.f;
      float e2 = acc1[r][j][2] + b; e2 = e2 > 0.f ? e2 : 0.f;
      float e3 = acc1[r][j][3] + b; e3 = e3 > 0.f ? e3 : 0.f;
      pkF[r][j].x = pkbf(e0, e1);
      pkF[r][j].y = pkbf(e2, e3);
    }
  }

  f32x4 acc2[4][10];
  #pragma unroll
  for (int r = 0; r < 4; ++r)
    #pragma unroll
    for (int j = 0; j < 10; ++j) acc2[r][j] = (f32x4){0.f,0.f,0.f,0.f};

  u16* Fb = lds;
  u16* W2b = &lds[16896];

  for (int hk = 0; hk < 2; ++hk){
    __syncthreads();
    if ((wave >> 1) == hk){
      int cl = (wave & 1)*128 + l16;
      #pragma unroll
      for (int j = 0; j < 8; ++j){
        int cc = cl + j*16;
        #pragma unroll
        for (int r = 0; r < 4; ++r){
          int row0 = r*16 + quad*4;
          Fb[(row0+0)*264 + cc] = (u16)(pkF[r][j].x);
          Fb[(row0+1)*264 + cc] = (u16)(pkF[r][j].x >> 16);
          Fb[(row0+2)*264 + cc] = (u16)(pkF[r][j].y);
          Fb[(row0+3)*264 + cc] = (u16)(pkF[r][j].y >> 16);
        }
      }
    }
    for (int h = 0; h < 2; ++h){
      for (int kc2 = 0; kc2 < 8; ++kc2){
        __syncthreads();
        for (int r = tid; r < 320; r += 256){
          const uint4* s = (const uint4*)(wvq_bf + (size_t)(h*320 + r)*DD + hk*256 + kc2*32);
          uint4* d = (uint4*)&W2b[r*40];
          d[0]=s[0]; d[1]=s[1]; d[2]=s[2]; d[3]=s[3];
        }
        __syncthreads();
        bf16x8 af0 = *(const bf16x8*)&Fb[(0*16 + l16)*264 + kc2*32 + quad*8];
        bf16x8 af1 = *(const bf16x8*)&Fb[(1*16 + l16)*264 + kc2*32 + quad*8];
        bf16x8 af2 = *(const bf16x8*)&Fb[(2*16 + l16)*264 + kc2*32 + quad*8];
        bf16x8 af3 = *(const bf16x8*)&Fb[(3*16 + l16)*264 + kc2*32 + quad*8];
        #pragma unroll
        for (int jj = 0; jj < 5; ++jj){
          bf16x8 wf = *(const bf16x8*)&W2b[(wave*80 + jj*16 + l16)*40 + quad*8];
          acc2[0][h*5+jj] = MFMA16(af0, wf, acc2[0][h*5+jj]);
          acc2[1][h*5+jj] = MFMA16(af1, wf, acc2[1][h*5+jj]);
          acc2[2][h*5+jj] = MFMA16(af2, wf, acc2[2][h*5+jj]);
          acc2[3][h*5+jj] = MFMA16(af3, wf, acc2[3][h*5+jj]);
        }
      }
    }
  }
  __syncthreads();

  float* Qf = (float*)lds;
  float* qL = (float*)&lds[16384];
  float* Ef = (float*)&lds[16896];

  qL[tid] = qmv[tid];
  #pragma unroll
  for (int t2 = 0; t2 < 10; ++t2){
    int h = t2 >= 5 ? 1 : 0;
    int col = h*320 + wave*80 + (t2 - h*5)*16 + l16;
    if (col >= 512){
      int qc = col - 512;
      float bqv = bq[qc];
      #pragma unroll
      for (int r = 0; r < 4; ++r)
        #pragma unroll
        for (int e = 0; e < 4; ++e){
          int row = r*16 + quad*4 + e;
          Qf[row*QD + qc] = tanhf(acc2[r][t2][e] + bqv);
        }
    } else {
      float bvv = bv[col];
      #pragma unroll
      for (int r = 0; r < 4; ++r)
        #pragma unroll
        for (int e = 0; e < 4; ++e) acc2[r][t2][e] += bvv;
    }
  }
  __syncthreads();

  {
    int row = tid >> 2, j = (tid >> 1) & 1, half = tid & 1;
    const float4* Ql = (const float4*)(Qf + row*QD + half*64);
    const float4* qv = (const float4*)(qL + j*QD + half*64);
    float s = 0.f;
    #pragma unroll
    for (int k = 0; k < 16; ++k){
      float4 x = Ql[k], w = qv[k];
      s += x.x*w.x + x.y*w.y + x.z*w.z + x.w*w.w;
    }
    s += __shfl_xor(s, 1);
    if (half == 0){
      bool valid = (i0 + row) < NROWS;
      float e = valid ? expf(s * 0.08838834764831845f) : 0.f;
      Ef[row*2 + j] = e;
      if (valid) Aout[(i0 + row)*2 + j] = e;
    }
  }
  __syncthreads();

  if (tid < 2){
    float ss = 0.f;
    for (int r = 0; r < 64; ++r) ss += Ef[r*2 + tid];
    atomicAdd(&sumE[tid], ss);
  }

  float er0[4][4], er1[4][4];
  #pragma unroll
  for (int r = 0; r < 4; ++r)
    #pragma unroll
    for (int e = 0; e < 4; ++e){
      int row = r*16 + quad*4 + e;
      er0[r][e] = Ef[row*2 + 0];
      er1[r][e] = Ef[row*2 + 1];
    }
  #pragma unroll
  for (int t2 = 0; t2 < 10; ++t2){
    int h = t2 >= 5 ? 1 : 0;
    int col = h*320 + wave*80 + (t2 - h*5)*16 + l16;
    if (col < 512){
      float b0 = 0.f, b1 = 0.f;
      #pragma unroll
      for (int r = 0; r < 4; ++r)
        #pragma unroll
        for (int e = 0; e < 4; ++e){
          float v = acc2[r][t2][e];
          b0 += v * er0[r][e];
          b1 += v * er1[r][e];
        }
      b0 += __shfl_xor(b0, 16); b0 += __shfl_xor(b0, 32);
      b1 += __shfl_xor(b1, 16); b1 += __shfl_xor(b1, 32);
      if (quad == 0){
        atomicAdd(&sumEV[col], b0);
        atomicAdd(&sumEV[512 + col], b1);
      }
    }
  }
}

__global__ void k_norm(float* __restrict__ Aout, const float* __restrict__ sumE){
  int idx = blockIdx.x*256 + threadIdx.x;
  if (idx < 200000) Aout[idx] = Aout[idx] / sumE[idx & 1];
}

__global__ void k_final(const float* __restrict__ sumEV, const float* __restrict__ sumE,
                        const float* __restrict__ Wfcc, const float* __restrict__ bfcc,
                        float* __restrict__ out){
  __shared__ float red[512];
  int t = threadIdx.x;
  float z0 = sumE[0], z1 = sumE[1];
  float c0 = 0.f, c1 = 0.f;
  for (int e = t; e < 1024; e += 256){
    float bvv = sumEV[e] / ((e >> 9) ? z1 : z0);
    out[200002 + e] = bvv;
    c0 += bvv * Wfcc[e];
    c1 += bvv * Wfcc[1024 + e];
  }
  red[t] = c0; red[256 + t] = c1;
  __syncthreads();
  for (int s = 128; s; s >>= 1){
    if (t < s){ red[t] += red[t + s]; red[256 + t] += red[256 + t + s]; }
    __syncthreads();
  }
  if (t == 0){ out[0] = red[0] + bfcc[0]; out[1] = red[256] + bfcc[1]; }
}

// ---------- launch ----------
extern "C" void kernel_launch(void* const* d_in, const int* in_sizes, int n_in,
                              void* d_out, int out_size, void* d_ws, size_t ws_size,
                              hipStream_t stream){
  (void)in_sizes; (void)n_in; (void)out_size;
  const float* feats = (const float*)d_in[0];
  const float* c     = (const float*)d_in[1];
  const float* preds = (const float*)d_in[2];
  const float* W_lin = (const float*)d_in[3];
  const float* b_lin = (const float*)d_in[4];
  const float* W_q   = (const float*)d_in[5];
  const float* b_q   = (const float*)d_in[6];
  const float* W_v   = (const float*)d_in[7];
  const float* b_v   = (const float*)d_in[8];
  const float* W_fcc = (const float*)d_in[9];
  const float* b_fcc = (const float*)d_in[10];
  float* out = (float*)d_out;
  char* ws = (char*)d_ws;

  // ws layout (bytes)
  u16*      wl_bf  = (u16*)(ws + 0);             // 524288
  u16*      wvq_bf = (u16*)(ws + 524288);        // 655360  -> 1179648
  uint32_t* hist1  = (uint32_t*)(ws + 1179648);  // 262144  -> 1441792
  uint32_t* hist2  = (uint32_t*)(ws + 1441792);  // 262144  -> 1703936
  Scal*     sc     = (Scal*)(ws + 1703936);      // 64      -> 1704000
  float*    fm     = (float*)(ws + 1704000);     // 4096    -> 1708096
  float*    qmv    = (float*)(ws + 1708096);     // 1024    -> 1709120
  float*    sumE   = (float*)(ws + 1709120);     // 64      -> 1709184
  float*    sumEV  = (float*)(ws + 1709184);     // 4096    -> 1713280
  float*    ews    = (float*)(ws + 1713280);     // 100096*2*4 = 800768 -> 2514048
  u16*      gx_ws  = (u16*)(ws + 2514048);       // 100096*512*2 = 102498304 -> 105012352
  u16*      f_ws   = (u16*)(ws + 105012352);     // 102498304 -> 207510656
  const bool big = ws_size >= 207510656ull;

  hipMemsetAsync(ws + 1179648, 0, 1713280 - 1179648, stream);

  k_conv  <<<2304, 256, 0, stream>>>(W_lin, W_v, W_q, wl_bf, wvq_bf);
  k_hist1 <<<391, 256, 0, stream>>>(preds, hist1);
  k_sel1  <<<1, 256, 0, stream>>>(hist1, sc);
  k_hist2 <<<391, 256, 0, stream>>>(preds, sc, hist2);
  k_sel2  <<<1, 256, 0, stream>>>(hist2, sc);
  k_sumexp<<<391, 256, 0, stream>>>(preds, sc);
  k_argc  <<<391, 256, 0, stream>>>(c, sc);
  k_mfeat <<<2, 256, 0, stream>>>(feats, preds, W_lin, b_lin, sc, fm);
  k_qmax  <<<1, 256, 0, stream>>>(fm, W_q, b_q, qmv);
  if (big){
    k_scale<<<25000, 256, 0, stream>>>(feats, preds, sc, gx_ws);
    k_f    <<<3128, 256, 0, stream>>>(gx_ws, wl_bf, b_lin, f_ws);
    k_q    <<<782, 256, 0, stream>>>(f_ws, wvq_bf, b_q, qmv, ews, sumE, out + 2);
    k_v    <<<3128, 256, 0, stream>>>(f_ws, wvq_bf, b_v, ews, sumEV);
  } else {
    k_main64<<<1563, 256, 0, stream>>>(feats, preds, wl_bf, wvq_bf, b_lin, b_v, b_q,
                                       qmv, sc, sumE, sumEV, out + 2);
  }
  k_norm  <<<782, 256, 0, stream>>>(out + 2, sumE);
  k_final <<<1, 256, 0, stream>>>(sumEV, sumE, W_fcc, b_fcc, out);
}

// Round 6
// 1045.224 us; speedup vs baseline: 1.3294x; 1.2538x over previous
//
#include <hip/hip_runtime.h>
#include <stdint.h>

typedef unsigned short u16;
typedef __bf16 bf16t;
typedef bf16t bf16x8 __attribute__((ext_vector_type(8)));
typedef float f32x4 __attribute__((ext_vector_type(4)));

#define NROWS 100000
#define DD 512
#define QD 128
#define KSEL 20000

// ---------- helpers ----------
__device__ __forceinline__ uint32_t fmono(float x){
  uint32_t u = __float_as_uint(x);
  return (u & 0x80000000u) ? ~u : (u | 0x80000000u);
}
__device__ __forceinline__ u16 f2bf(float x){  // RNE float->bf16 bits
  uint32_t u = __float_as_uint(x);
  u += 0x7fffu + ((u >> 16) & 1u);
  return (u16)(u >> 16);
}
__device__ __forceinline__ uint32_t pkbf(float a, float b){
  return (uint32_t)f2bf(a) | ((uint32_t)f2bf(b) << 16);
}

struct Scal {
  uint32_t keyT;
  float Z;
  uint32_t pad[14];
};

#define MFMA16(A,B,C) __builtin_amdgcn_mfma_f32_16x16x32_bf16(A,B,C,0,0,0)

// ---------- k_conv: fp32 weights -> bf16 (proven) ----------
__global__ void k_conv(const float* __restrict__ Wl, const float* __restrict__ Wv,
                       const float* __restrict__ Wq, u16* __restrict__ wl_bf, u16* __restrict__ wvq_bf){
  int idx = blockIdx.x*256 + threadIdx.x;          // 589824 total
  if (idx < 262144) wl_bf[idx] = f2bf(Wl[idx]);
  int e = idx - 262144;
  if (e >= 0) wvq_bf[e] = f2bf(e < 262144 ? Wv[e] : Wq[e - 262144]);
}

// ---------- k_prep: one block does the whole scalar pre-chain ----------
// 4-pass 256-bin radix select (keyT), Z = sum exp, argmax of c cols,
// exact fp32 m_feats, q_max -> qmv. Writes sc{keyT,Z}, qmv[256].
__launch_bounds__(1024)
__global__ void k_prep(const float* __restrict__ preds, const float* __restrict__ c,
                       const float* __restrict__ feats,
                       const float* __restrict__ Wl, const float* __restrict__ bl,
                       const float* __restrict__ Wq, const float* __restrict__ bq,
                       Scal* __restrict__ sc, float* __restrict__ qmv){
  __shared__ uint32_t hist[256];
  __shared__ uint32_t s_b, s_cum;
  __shared__ float zred[16];
  __shared__ unsigned long long kred[2][16];
  __shared__ uint32_t s_mi[2];
  __shared__ float s_Z;
  __shared__ float fmX[2][512];
  __shared__ float fmF[2][512];
  const int t = threadIdx.x;
  const int lane = t & 63, wv = t >> 6;

  // ---- 4-pass radix select over monotone keys ----
  uint32_t prefix = 0, target = KSEL;
  for (int pass = 0; pass < 4; ++pass){
    int shift = 24 - pass*8;
    if (t < 256) hist[t] = 0u;
    __syncthreads();
    uint32_t mask = pass ? (0xFFFFFFFFu << (shift + 8)) : 0u;
    for (int i = t; i < NROWS; i += 1024){
      uint32_t k = fmono(preds[i]);
      if ((k & mask) == prefix) atomicAdd(&hist[(k >> shift) & 0xFFu], 1u);
    }
    __syncthreads();
    if (t == 0){
      uint32_t cum = 0;
      for (int b = 0; b < 256; ++b){
        uint32_t h = hist[b];
        if (cum + h >= target){ s_b = (uint32_t)b; s_cum = cum; break; }
        cum += h;
      }
    }
    __syncthreads();
    prefix |= s_b << shift;
    target -= s_cum;
    __syncthreads();
  }
  const uint32_t keyT = prefix;

  // ---- Z = sum(exp(pm)) and argmax keys of c columns ----
  float s = 0.f;
  unsigned long long k0 = 0ull, k1 = 0ull;
  for (int i = t; i < NROWS; i += 1024){
    float p = preds[i];
    float pm = (fmono(p) <= keyT) ? 0.f : p;
    s += __expf(pm);
    uint32_t inv = ~(uint32_t)i;
    unsigned long long a0 = ((unsigned long long)fmono(c[(size_t)i*2 + 0]) << 32) | inv;
    unsigned long long a1 = ((unsigned long long)fmono(c[(size_t)i*2 + 1]) << 32) | inv;
    if (a0 > k0) k0 = a0;
    if (a1 > k1) k1 = a1;
  }
  #pragma unroll
  for (int off = 32; off; off >>= 1){
    s += __shfl_xor(s, off);
    unsigned long long o0 = __shfl_xor(k0, off); if (o0 > k0) k0 = o0;
    unsigned long long o1 = __shfl_xor(k1, off); if (o1 > k1) k1 = o1;
  }
  if (lane == 0){ zred[wv] = s; kred[0][wv] = k0; kred[1][wv] = k1; }
  __syncthreads();
  if (t == 0){
    float Z = 0.f; unsigned long long m0 = 0ull, m1 = 0ull;
    for (int w = 0; w < 16; ++w){
      Z += zred[w];
      if (kred[0][w] > m0) m0 = kred[0][w];
      if (kred[1][w] > m1) m1 = kred[1][w];
    }
    sc->keyT = keyT; sc->Z = Z; s_Z = Z;
    s_mi[0] = ~(uint32_t)(m0 & 0xffffffffull);
    s_mi[1] = ~(uint32_t)(m1 & 0xffffffffull);
  }
  __syncthreads();

  // ---- load the 2 argmax feats rows ----
  {
    int j = t >> 9, col = t & 511;
    fmX[j][col] = feats[(size_t)s_mi[j]*DD + col];
  }
  __syncthreads();

  // ---- exact fp32 m_feats ----
  {
    int n = t >> 1, h = t & 1;
    const float4* wr4 = (const float4*)(Wl + (size_t)n*DD + h*256);
    const float4* x04 = (const float4*)(&fmX[0][h*256]);
    const float4* x14 = (const float4*)(&fmX[1][h*256]);
    float a0 = 0.f, a1 = 0.f;
    #pragma unroll 4
    for (int k = 0; k < 64; ++k){
      float4 w = wr4[k], u = x04[k], v = x14[k];
      a0 += u.x*w.x + u.y*w.y + u.z*w.z + u.w*w.w;
      a1 += v.x*w.x + v.y*w.y + v.z*w.z + v.w*w.w;
    }
    a0 += __shfl_xor(a0, 1);
    a1 += __shfl_xor(a1, 1);
    if (h == 0){
      float Z = s_Z;
      float p0 = preds[s_mi[0]]; float q0 = (fmono(p0) <= keyT) ? 0.f : p0;
      float g0 = 1.f + __expf(q0) / Z;
      float p1 = preds[s_mi[1]]; float q1 = (fmono(p1) <= keyT) ? 0.f : p1;
      float g1 = 1.f + __expf(q1) / Z;
      float v0 = bl[n] + g0*a0; fmF[0][n] = v0 > 0.f ? v0 : 0.f;
      float v1 = bl[n] + g1*a1; fmF[1][n] = v1 > 0.f ? v1 : 0.f;
    }
  }
  __syncthreads();

  // ---- q_max ----
  if (t < 256){
    int q = t & 127, j = t >> 7;
    const float4* wr4 = (const float4*)(Wq + (size_t)q*DD);
    const float4* x4  = (const float4*)(fmF[j]);
    float a0 = 0.f, a1 = 0.f;
    #pragma unroll 4
    for (int k = 0; k < 128; k += 2){
      float4 w0 = wr4[k], u0 = x4[k];
      float4 w1 = wr4[k+1], u1 = x4[k+1];
      a0 += u0.x*w0.x + u0.y*w0.y + u0.z*w0.z + u0.w*w0.w;
      a1 += u1.x*w1.x + u1.y*w1.y + u1.z*w1.z + u1.w*w1.w;
    }
    qmv[j*QD + q] = tanhf(bq[q] + a0 + a1);
  }
}

// ---------- weight chunk source: linear chunk index ci = 0..143 ----------
// ci 0..63: stage1, Wl col-tiles nt(4) x kc(16).  ci 64..143: stage2 over wvq:
// nt2 0 = Q cols (512..639) FIRST, nt2 1..4 = V cols 0..511.
__device__ __forceinline__ const u16* chunk_src(const u16* __restrict__ wl,
                                                const u16* __restrict__ wvq,
                                                int ci, int r, int p){
  if (ci < 64){
    int nt = ci >> 4, kc = ci & 15;
    return wl + (size_t)(nt*128 + r)*DD + kc*32 + p*16;
  }
  int c2 = ci - 64;
  int nt2 = c2 >> 4, kc = c2 & 15;
  int colbase = (nt2 == 0) ? 512 : (nt2 - 1)*128;
  return wvq + (size_t)(colbase + r)*DD + kc*32 + p*16;
}

// ---------- k_fused: the whole heavy pipeline, feats read ONCE ----------
// Block = 32 rows. LDS: AF [32][520] u16 (gX tile, later overwritten by F tile),
// Wb [128][40] u16 (weight chunk, 128 cols x 32 k), Ef 64 f32, sumEVl 2048 f32.
// 4 waves: wm=wave>>1 (row half), wn=wave&1 (col half). acc = 16 VGPR. No spill.
__launch_bounds__(256, 3)
__global__ void k_fused(const float* __restrict__ feats, const float* __restrict__ preds,
                        const u16* __restrict__ wl, const u16* __restrict__ wvq,
                        const float* __restrict__ bl, const float* __restrict__ bv,
                        const float* __restrict__ bq, const float* __restrict__ qmv,
                        const Scal* __restrict__ sc,
                        float* __restrict__ gpart, float* __restrict__ gpartE,
                        float* __restrict__ Aout){
  __shared__ __align__(16) u16 lds[21888];
  __shared__ __align__(16) float sumEVl[2048];   // [wm][j*512 + col]
  u16* AF = lds;                        // [32][520]
  u16* Wb = lds + 16640;                // [128][40]
  float* sred = (float*)(lds + 16640);  // overlay on Wb: [32 rows][2 j][2 wn]
  float* Ef   = (float*)(lds + 21760);  // [32][2]
  const int tid = threadIdx.x;
  const int lane = tid & 63, quad = lane >> 4, l16 = lane & 15;
  const int wave = tid >> 6, wm = wave >> 1, wn = wave & 1;
  const long i0 = (long)blockIdx.x * 32;
  const uint32_t keyT = sc->keyT;
  const float Z = sc->Z;

  // ---- stage gX tile (32 x 512) into LDS as bf16, g folded ----
  {
    int row = tid >> 3, q8 = tid & 7;
    long ir = i0 + row; if (ir >= NROWS) ir = NROWS - 1;
    float p = preds[ir];
    float pm = (fmono(p) <= keyT) ? 0.f : p;
    float g = 1.f + __expf(pm) / Z;
    const float4* src = (const float4*)(feats + ir*DD + q8*64);
    u16* dst = AF + row*520 + q8*64;
    #pragma unroll
    for (int j = 0; j < 8; ++j){
      float4 a = src[2*j], b = src[2*j + 1];
      uint4 pk;
      pk.x = pkbf(a.x*g, a.y*g); pk.y = pkbf(a.z*g, a.w*g);
      pk.z = pkbf(b.x*g, b.y*g); pk.w = pkbf(b.z*g, b.w*g);
      *(uint4*)(dst + j*8) = pk;
    }
  }

  const int rS = tid >> 1, pS = tid & 1;
  u16* wdst = Wb + rS*40 + pS*16;
  uint4 w0, w1;
  { const u16* sp = chunk_src(wl, wvq, 0, rS, pS); w0 = *(const uint4*)sp; w1 = *(const uint4*)(sp + 8); }

  f32x4 acc[4];
  #pragma unroll
  for (int ni = 0; ni < 4; ++ni) acc[ni] = (f32x4){0.f,0.f,0.f,0.f};
  uint32_t pkF[32];
  int ci = 0;

  // ---- stage 1: f = relu(gX @ Wl^T + bl), kept in pkF registers ----
  for (int nt = 0; nt < 4; ++nt){
    for (int kc = 0; kc < 16; ++kc, ++ci){
      __syncthreads();
      *(uint4*)wdst = w0; *(uint4*)(wdst + 8) = w1;
      __syncthreads();
      if (ci < 143){
        const u16* sp = chunk_src(wl, wvq, ci + 1, rS, pS);
        w0 = *(const uint4*)sp; w1 = *(const uint4*)(sp + 8);
      }
      bf16x8 af = *(const bf16x8*)&AF[(wm*16 + l16)*520 + kc*32 + quad*8];
      #pragma unroll
      for (int ni = 0; ni < 4; ++ni){
        bf16x8 bfr = *(const bf16x8*)&Wb[(wn*64 + ni*16 + l16)*40 + quad*8];
        acc[ni] = MFMA16(af, bfr, acc[ni]);
      }
    }
    #pragma unroll
    for (int ni = 0; ni < 4; ++ni){
      float bb = bl[nt*128 + wn*64 + ni*16 + l16];
      float e0 = acc[ni][0] + bb; e0 = e0 > 0.f ? e0 : 0.f;
      float e1 = acc[ni][1] + bb; e1 = e1 > 0.f ? e1 : 0.f;
      float e2 = acc[ni][2] + bb; e2 = e2 > 0.f ? e2 : 0.f;
      float e3 = acc[ni][3] + bb; e3 = e3 > 0.f ? e3 : 0.f;
      pkF[nt*8 + ni*2 + 0] = pkbf(e0, e1);
      pkF[nt*8 + ni*2 + 1] = pkbf(e2, e3);
      acc[ni] = (f32x4){0.f,0.f,0.f,0.f};
    }
  }

  // ---- transpose pkF (C-layout) -> F tile in LDS (A-operand layout), overwrite AF ----
  __syncthreads();   // all stage-1 A reads done
  #pragma unroll
  for (int nt = 0; nt < 4; ++nt)
    #pragma unroll
    for (int ni = 0; ni < 4; ++ni){
      int col = nt*128 + wn*64 + ni*16 + l16;
      int r0 = (wm*16 + quad*4)*520 + col;
      uint32_t x = pkF[nt*8 + ni*2], y = pkF[nt*8 + ni*2 + 1];
      AF[r0]        = (u16)x;
      AF[r0 + 520]  = (u16)(x >> 16);
      AF[r0 + 1040] = (u16)y;
      AF[r0 + 1560] = (u16)(y >> 16);
    }
  // visibility via next loop-top barrier

  // ---- stage 2: [Q|V] = f @ W^T ; Q first (-> e), then V weighted by e ----
  for (int nt2 = 0; nt2 < 5; ++nt2){
    for (int kc = 0; kc < 16; ++kc, ++ci){
      __syncthreads();
      *(uint4*)wdst = w0; *(uint4*)(wdst + 8) = w1;
      __syncthreads();
      if (ci < 143){
        const u16* sp = chunk_src(wl, wvq, ci + 1, rS, pS);
        w0 = *(const uint4*)sp; w1 = *(const uint4*)(sp + 8);
      }
      bf16x8 af = *(const bf16x8*)&AF[(wm*16 + l16)*520 + kc*32 + quad*8];
      #pragma unroll
      for (int ni = 0; ni < 4; ++ni){
        bf16x8 bfr = *(const bf16x8*)&Wb[(wn*64 + ni*16 + l16)*40 + quad*8];
        acc[ni] = MFMA16(af, bfr, acc[ni]);
      }
    }
    if (nt2 == 0){
      // ---- Q epilogue: tanh, dot with qmv, e = exp(score/sqrt(128)) ----
      float p0[4], p1[4];
      #pragma unroll
      for (int e = 0; e < 4; ++e){ p0[e] = 0.f; p1[e] = 0.f; }
      #pragma unroll
      for (int ni = 0; ni < 4; ++ni){
        int qc = wn*64 + ni*16 + l16;
        float bqv = bq[qc], q0 = qmv[qc], q1 = qmv[QD + qc];
        #pragma unroll
        for (int e = 0; e < 4; ++e){
          float tq = tanhf(acc[ni][e] + bqv);
          p0[e] += tq * q0;
          p1[e] += tq * q1;
        }
        acc[ni] = (f32x4){0.f,0.f,0.f,0.f};
      }
      #pragma unroll
      for (int off = 1; off <= 8; off <<= 1)
        #pragma unroll
        for (int e = 0; e < 4; ++e){
          p0[e] += __shfl_xor(p0[e], off);
          p1[e] += __shfl_xor(p1[e], off);
        }
      __syncthreads();   // Wb MFMA reads done before sred overlay write
      if (l16 == 0){
        #pragma unroll
        for (int e = 0; e < 4; ++e){
          int row = wm*16 + quad*4 + e;
          sred[(row*2 + 0)*2 + wn] = p0[e];
          sred[(row*2 + 1)*2 + wn] = p1[e];
        }
      }
      __syncthreads();
      if (tid < 64){
        int row = tid >> 1, j = tid & 1;
        float sv = (sred[(row*2 + j)*2 + 0] + sred[(row*2 + j)*2 + 1]) * 0.08838834764831845f;
        bool valid = (i0 + row) < NROWS;
        float ev = valid ? __expf(sv) : 0.f;
        Ef[row*2 + j] = ev;
        if (valid) Aout[(i0 + row)*2 + j] = ev;
        float t2 = ev;
        #pragma unroll
        for (int off = 2; off <= 32; off <<= 1) t2 += __shfl_xor(t2, off);
        if (lane < 2) gpartE[(size_t)blockIdx.x*2 + j] = t2;
      }
      __syncthreads();   // Ef visible; sred reads done before next Wb store
    } else {
      // ---- V epilogue: e-weighted column sums into per-block LDS ----
      float e0[4], e1[4];
      #pragma unroll
      for (int e = 0; e < 4; ++e){
        int row = wm*16 + quad*4 + e;
        e0[e] = Ef[row*2 + 0];
        e1[e] = Ef[row*2 + 1];
      }
      #pragma unroll
      for (int ni = 0; ni < 4; ++ni){
        int colv = (nt2 - 1)*128 + wn*64 + ni*16 + l16;
        float bvv = bv[colv];
        float b0 = 0.f, b1 = 0.f;
        #pragma unroll
        for (int e = 0; e < 4; ++e){
          float v = acc[ni][e] + bvv;
          b0 += v * e0[e];
          b1 += v * e1[e];
        }
        b0 += __shfl_xor(b0, 16); b0 += __shfl_xor(b0, 32);
        b1 += __shfl_xor(b1, 16); b1 += __shfl_xor(b1, 32);
        if (quad == 0){
          sumEVl[wm*1024 + colv]       = b0;
          sumEVl[wm*1024 + 512 + colv] = b1;
        }
        acc[ni] = (f32x4){0.f,0.f,0.f,0.f};
      }
    }
  }
  __syncthreads();
  #pragma unroll
  for (int k2 = 0; k2 < 4; ++k2){
    int x = k2*256 + tid;
    gpart[(size_t)blockIdx.x*1024 + x] = sumEVl[x] + sumEVl[1024 + x];
  }
}

// ---------- k_red: reduce per-block partials -> sumEV[1024], sumE[2] ----------
__global__ void k_red(const float* __restrict__ gpart, const float* __restrict__ gpartE,
                      float* __restrict__ sumEV, float* __restrict__ sumE){
  const int bid = blockIdx.x, t = threadIdx.x;
  if (bid < 4){
    int x = bid*256 + t;
    float s = 0.f;
    for (int b = 0; b < 3125; ++b) s += gpart[(size_t)b*1024 + x];
    sumEV[x] = s;
  } else {
    __shared__ float r0[256], r1[256];
    float s0 = 0.f, s1 = 0.f;
    for (int b = t; b < 3125; b += 256){ s0 += gpartE[(size_t)b*2]; s1 += gpartE[(size_t)b*2 + 1]; }
    r0[t] = s0; r1[t] = s1;
    __syncthreads();
    for (int st = 128; st; st >>= 1){
      if (t < st){ r0[t] += r0[t + st]; r1[t] += r1[t + st]; }
      __syncthreads();
    }
    if (t == 0){ sumE[0] = r0[0]; sumE[1] = r1[0]; }
  }
}

// ---------- k_post: normalize A; compute B and Cout ----------
__global__ void k_post(float* __restrict__ out, const float* __restrict__ sumE,
                       const float* __restrict__ sumEV, const float* __restrict__ Wfcc,
                       const float* __restrict__ bfcc){
  if (blockIdx.x < 782){
    int idx = blockIdx.x*256 + threadIdx.x;
    if (idx < 200000) out[2 + idx] = out[2 + idx] / sumE[idx & 1];
    return;
  }
  __shared__ float red[512];
  int t = threadIdx.x;
  float z0 = sumE[0], z1 = sumE[1];
  float c0 = 0.f, c1 = 0.f;
  for (int e = t; e < 1024; e += 256){
    float bvv = sumEV[e] / ((e >> 9) ? z1 : z0);
    out[200002 + e] = bvv;
    c0 += bvv * Wfcc[e];
    c1 += bvv * Wfcc[1024 + e];
  }
  red[t] = c0; red[256 + t] = c1;
  __syncthreads();
  for (int s = 128; s; s >>= 1){
    if (t < s){ red[t] += red[t + s]; red[256 + t] += red[256 + t + s]; }
    __syncthreads();
  }
  if (t == 0){ out[0] = red[0] + bfcc[0]; out[1] = red[256] + bfcc[1]; }
}

// ---------- launch ----------
extern "C" void kernel_launch(void* const* d_in, const int* in_sizes, int n_in,
                              void* d_out, int out_size, void* d_ws, size_t ws_size,
                              hipStream_t stream){
  (void)in_sizes; (void)n_in; (void)out_size; (void)ws_size;
  const float* feats = (const float*)d_in[0];
  const float* c     = (const float*)d_in[1];
  const float* preds = (const float*)d_in[2];
  const float* W_lin = (const float*)d_in[3];
  const float* b_lin = (const float*)d_in[4];
  const float* W_q   = (const float*)d_in[5];
  const float* b_q   = (const float*)d_in[6];
  const float* W_v   = (const float*)d_in[7];
  const float* b_v   = (const float*)d_in[8];
  const float* W_fcc = (const float*)d_in[9];
  const float* b_fcc = (const float*)d_in[10];
  float* out = (float*)d_out;
  char* ws = (char*)d_ws;

  // ws layout (bytes) — every region fully rewritten each call; no memset needed
  u16*   wl_bf  = (u16*)(ws + 0);            // 524288
  u16*   wvq_bf = (u16*)(ws + 524288);       // 655360   -> 1179648
  Scal*  sc     = (Scal*)(ws + 1179648);     // 64       -> 1179712
  float* qmv    = (float*)(ws + 1179712);    // 1024     -> 1180736
  float* sumE   = (float*)(ws + 1180736);    // 64       -> 1180800
  float* sumEV  = (float*)(ws + 1180800);    // 4096     -> 1184896
  float* gpartE = (float*)(ws + 1184896);    // 3125*2*4 = 25000 (pad 25600) -> 1210496
  float* gpart  = (float*)(ws + 1210496);    // 3125*1024*4 = 12800000 -> 14010496

  k_conv <<<2304, 256, 0, stream>>>(W_lin, W_v, W_q, wl_bf, wvq_bf);
  k_prep <<<1, 1024, 0, stream>>>(preds, c, feats, W_lin, b_lin, W_q, b_q, sc, qmv);
  k_fused<<<3125, 256, 0, stream>>>(feats, preds, wl_bf, wvq_bf, b_lin, b_v, b_q,
                                    qmv, sc, gpart, gpartE, out + 2);
  k_red  <<<5, 256, 0, stream>>>(gpart, gpartE, sumEV, sumE);
  k_post <<<783, 256, 0, stream>>>(out, sumE, sumEV, W_fcc, b_fcc);
}

// Round 7
// 784.913 us; speedup vs baseline: 1.7703x; 1.3316x over previous
//
#include <hip/hip_runtime.h>
#include <stdint.h>

typedef unsigned short u16;
typedef __bf16 bf16t;
typedef bf16t bf16x8 __attribute__((ext_vector_type(8)));
typedef float f32x4 __attribute__((ext_vector_type(4)));
typedef unsigned long long ull;

#define NROWS 100000
#define DD 512
#define QD 128
#define KSEL 20000
#define NB 1563   // ceil(100000/64)

// ---------- helpers ----------
__device__ __forceinline__ uint32_t fmono(float x){
  uint32_t u = __float_as_uint(x);
  return (u & 0x80000000u) ? ~u : (u | 0x80000000u);
}
__device__ __forceinline__ u16 f2bf(float x){  // RNE float->bf16 bits
  uint32_t u = __float_as_uint(x);
  u += 0x7fffu + ((u >> 16) & 1u);
  return (u16)(u >> 16);
}
__device__ __forceinline__ uint32_t pkbf(float a, float b){
  return (uint32_t)f2bf(a) | ((uint32_t)f2bf(b) << 16);
}

struct Scal {
  uint32_t keyT;
  float Z;
  uint32_t pad[14];
};

#define MFMA16(A,B,C) __builtin_amdgcn_mfma_f32_16x16x32_bf16(A,B,C,0,0,0)

// ---------- k_conv: fp32 weights -> bf16 (proven) ----------
__global__ void k_conv(const float* __restrict__ Wl, const float* __restrict__ Wv,
                       const float* __restrict__ Wq, u16* __restrict__ wl_bf, u16* __restrict__ wvq_bf){
  int idx = blockIdx.x*256 + threadIdx.x;          // 589824 total
  if (idx < 262144) wl_bf[idx] = f2bf(Wl[idx]);
  int e = idx - 262144;
  if (e >= 0) wvq_bf[e] = f2bf(e < 262144 ? Wv[e] : Wq[e - 262144]);
}

// ---------- k_prep: one block, whole scalar pre-chain (float4-vectorized) ----------
__launch_bounds__(1024)
__global__ void k_prep(const float* __restrict__ preds, const float* __restrict__ c,
                       const float* __restrict__ feats,
                       const float* __restrict__ Wl, const float* __restrict__ bl,
                       const float* __restrict__ Wq, const float* __restrict__ bq,
                       Scal* __restrict__ sc, float* __restrict__ qmv){
  __shared__ uint32_t hist[256];
  __shared__ uint32_t s_b, s_cum;
  __shared__ float zred[16];
  __shared__ ull kred[2][16];
  __shared__ uint32_t s_mi[2];
  __shared__ float s_Z;
  __shared__ float fmX[2][512];
  __shared__ float fmF[2][512];
  const int t = threadIdx.x;
  const int lane = t & 63, wv = t >> 6;
  const float4* p4 = (const float4*)preds;

  // ---- 4-pass radix select over monotone keys ----
  uint32_t prefix = 0, target = KSEL;
  for (int pass = 0; pass < 4; ++pass){
    int shift = 24 - pass*8;
    if (t < 256) hist[t] = 0u;
    __syncthreads();
    uint32_t mask = pass ? (0xFFFFFFFFu << (shift + 8)) : 0u;
    for (int i = t; i < 25000; i += 1024){
      float4 v = p4[i];
      uint32_t k0 = fmono(v.x), k1 = fmono(v.y), k2 = fmono(v.z), k3 = fmono(v.w);
      if ((k0 & mask) == prefix) atomicAdd(&hist[(k0 >> shift) & 0xFFu], 1u);
      if ((k1 & mask) == prefix) atomicAdd(&hist[(k1 >> shift) & 0xFFu], 1u);
      if ((k2 & mask) == prefix) atomicAdd(&hist[(k2 >> shift) & 0xFFu], 1u);
      if ((k3 & mask) == prefix) atomicAdd(&hist[(k3 >> shift) & 0xFFu], 1u);
    }
    __syncthreads();
    if (t == 0){
      uint32_t cum = 0;
      for (int b = 0; b < 256; ++b){
        uint32_t h = hist[b];
        if (cum + h >= target){ s_b = (uint32_t)b; s_cum = cum; break; }
        cum += h;
      }
    }
    __syncthreads();
    prefix |= s_b << shift;
    target -= s_cum;
    __syncthreads();
  }
  const uint32_t keyT = prefix;

  // ---- Z = sum(exp(pm)) ----
  float s = 0.f;
  for (int i = t; i < 25000; i += 1024){
    float4 v = p4[i];
    float m0 = (fmono(v.x) <= keyT) ? 0.f : v.x;
    float m1 = (fmono(v.y) <= keyT) ? 0.f : v.y;
    float m2 = (fmono(v.z) <= keyT) ? 0.f : v.z;
    float m3 = (fmono(v.w) <= keyT) ? 0.f : v.w;
    s += __expf(m0) + __expf(m1) + __expf(m2) + __expf(m3);
  }
  // ---- argmax keys of c columns ----
  ull k0 = 0ull, k1 = 0ull;
  const float4* c4 = (const float4*)c;
  for (int i = t; i < 50000; i += 1024){
    float4 v = c4[i];             // rows 2i (x=c0,y=c1), 2i+1 (z=c0,w=c1)
    uint32_t r0 = 2u*i, r1 = 2u*i + 1u;
    ull a0 = ((ull)fmono(v.x) << 32) | (ull)(~r0);
    ull a1 = ((ull)fmono(v.z) << 32) | (ull)(~r1);
    ull b0 = ((ull)fmono(v.y) << 32) | (ull)(~r0);
    ull b1 = ((ull)fmono(v.w) << 32) | (ull)(~r1);
    if (a0 > k0) k0 = a0;
    if (a1 > k0) k0 = a1;
    if (b0 > k1) k1 = b0;
    if (b1 > k1) k1 = b1;
  }
  #pragma unroll
  for (int off = 32; off; off >>= 1){
    s += __shfl_xor(s, off);
    ull o0 = __shfl_xor(k0, off); if (o0 > k0) k0 = o0;
    ull o1 = __shfl_xor(k1, off); if (o1 > k1) k1 = o1;
  }
  if (lane == 0){ zred[wv] = s; kred[0][wv] = k0; kred[1][wv] = k1; }
  __syncthreads();
  if (t == 0){
    float Z = 0.f; ull m0 = 0ull, m1 = 0ull;
    for (int w = 0; w < 16; ++w){
      Z += zred[w];
      if (kred[0][w] > m0) m0 = kred[0][w];
      if (kred[1][w] > m1) m1 = kred[1][w];
    }
    sc->keyT = keyT; sc->Z = Z; s_Z = Z;
    s_mi[0] = ~(uint32_t)(m0 & 0xffffffffull);
    s_mi[1] = ~(uint32_t)(m1 & 0xffffffffull);
  }
  __syncthreads();

  // ---- load the 2 argmax feats rows ----
  {
    int j = t >> 9, col = t & 511;
    fmX[j][col] = feats[(size_t)s_mi[j]*DD + col];
  }
  __syncthreads();

  // ---- exact fp32 m_feats ----
  {
    int n = t >> 1, h = t & 1;
    const float4* wr4 = (const float4*)(Wl + (size_t)n*DD + h*256);
    const float4* x04 = (const float4*)(&fmX[0][h*256]);
    const float4* x14 = (const float4*)(&fmX[1][h*256]);
    float a0 = 0.f, a1 = 0.f;
    #pragma unroll 4
    for (int k = 0; k < 64; ++k){
      float4 w = wr4[k], u = x04[k], v = x14[k];
      a0 += u.x*w.x + u.y*w.y + u.z*w.z + u.w*w.w;
      a1 += v.x*w.x + v.y*w.y + v.z*w.z + v.w*w.w;
    }
    a0 += __shfl_xor(a0, 1);
    a1 += __shfl_xor(a1, 1);
    if (h == 0){
      float Z = s_Z;
      float p0 = preds[s_mi[0]]; float q0 = (fmono(p0) <= keyT) ? 0.f : p0;
      float g0 = 1.f + __expf(q0) / Z;
      float p1 = preds[s_mi[1]]; float q1 = (fmono(p1) <= keyT) ? 0.f : p1;
      float g1 = 1.f + __expf(q1) / Z;
      float v0 = bl[n] + g0*a0; fmF[0][n] = v0 > 0.f ? v0 : 0.f;
      float v1 = bl[n] + g1*a1; fmF[1][n] = v1 > 0.f ? v1 : 0.f;
    }
  }
  __syncthreads();

  // ---- q_max ----
  if (t < 256){
    int q = t & 127, j = t >> 7;
    const float4* wr4 = (const float4*)(Wq + (size_t)q*DD);
    const float4* x4  = (const float4*)(fmF[j]);
    float a0 = 0.f, a1 = 0.f;
    #pragma unroll 4
    for (int k = 0; k < 128; k += 2){
      float4 w0 = wr4[k], u0 = x4[k];
      float4 w1 = wr4[k+1], u1 = x4[k+1];
      a0 += u0.x*w0.x + u0.y*w0.y + u0.z*w0.z + u0.w*w0.w;
      a1 += u1.x*w1.x + u1.y*w1.y + u1.z*w1.z + u1.w*w1.w;
    }
    qmv[j*QD + q] = tanhf(bq[q] + a0 + a1);
  }
}

// ---------- weight chunk source: linear chunk index ci = 0..143 ----------
__device__ __forceinline__ const u16* chunk_src(const u16* __restrict__ wl,
                                                const u16* __restrict__ wvq,
                                                int ci, int r, int p){
  if (ci < 64){
    int nt = ci >> 4, kc = ci & 15;
    return wl + (size_t)(nt*128 + r)*DD + kc*32 + p*16;
  }
  int c2 = ci - 64;
  int nt2 = c2 >> 4, kc = c2 & 15;
  int colbase = (nt2 == 0) ? 512 : (nt2 - 1)*128;
  return wvq + (size_t)(colbase + r)*DD + kc*32 + p*16;
}

// ---------- k_fused: M=64, 2x2 wave grid, wave tile 32x64 ----------
// LDS (u16): AF [64][520] @0 (33280); Wb [128][40] @33280 (5120) -> 38400 u16 = 76.8KB
// sred overlays Wb (256 f32); Ef separate 128 f32.
__launch_bounds__(256, 2)
__global__ void k_fused(const float* __restrict__ feats, const float* __restrict__ preds,
                        const u16* __restrict__ wl, const u16* __restrict__ wvq,
                        const float* __restrict__ bl, const float* __restrict__ bv,
                        const float* __restrict__ bq, const float* __restrict__ qmv,
                        const Scal* __restrict__ sc,
                        float* __restrict__ gpart, float* __restrict__ gpartE,
                        float* __restrict__ Aout){
  __shared__ __align__(16) u16 lds[38400];
  __shared__ __align__(16) float Ef[128];
  u16* AF = lds;                        // [64][520]
  u16* Wb = lds + 33280;                // [128][40]
  float* sred = (float*)(lds + 33280);  // overlay: [64 rows][2 j][2 wn]
  const int tid = threadIdx.x;
  const int lane = tid & 63, quad = lane >> 4, l16 = lane & 15;
  const int wave = tid >> 6, wm = wave >> 1, wn = wave & 1;
  const long i0 = (long)blockIdx.x * 64;
  const uint32_t keyT = sc->keyT;
  const float Z = sc->Z;

  // ---- stage gX tile (64 x 512) into LDS as bf16, g folded; row = lane ----
  {
    int row = lane;
    long ir = i0 + row; if (ir >= NROWS) ir = NROWS - 1;
    float p = preds[ir];
    float pm = (fmono(p) <= keyT) ? 0.f : p;
    float g = 1.f + __expf(pm) / Z;
    const float4* src = (const float4*)(feats + ir*DD + wave*128);
    u16* dst = AF + row*520 + wave*128;
    #pragma unroll
    for (int j = 0; j < 16; ++j){
      float4 a = src[2*j], b = src[2*j + 1];
      uint4 pk;
      pk.x = pkbf(a.x*g, a.y*g); pk.y = pkbf(a.z*g, a.w*g);
      pk.z = pkbf(b.x*g, b.y*g); pk.w = pkbf(b.z*g, b.w*g);
      *(uint4*)(dst + j*8) = pk;
    }
  }

  const int rS = tid >> 1, pS = tid & 1;
  u16* wdst = Wb + rS*40 + pS*16;
  uint4 w0, w1;
  { const u16* sp = chunk_src(wl, wvq, 0, rS, pS); w0 = *(const uint4*)sp; w1 = *(const uint4*)(sp + 8); }

  f32x4 acc[2][4];
  uint32_t pkF[4][16];
  int ci = 0;

  // ---- stage 1: f = relu(gX @ Wl^T + bl) -> pkF registers ----
  for (int nt = 0; nt < 4; ++nt){
    #pragma unroll
    for (int mi = 0; mi < 2; ++mi)
      #pragma unroll
      for (int ni = 0; ni < 4; ++ni) acc[mi][ni] = (f32x4){0.f,0.f,0.f,0.f};
    for (int kc = 0; kc < 16; ++kc, ++ci){
      __syncthreads();
      *(uint4*)wdst = w0; *(uint4*)(wdst + 8) = w1;
      __syncthreads();
      if (ci < 143){
        const u16* sp = chunk_src(wl, wvq, ci + 1, rS, pS);
        w0 = *(const uint4*)sp; w1 = *(const uint4*)(sp + 8);
      }
      bf16x8 a0 = *(const bf16x8*)&AF[(wm*32 + l16)*520 + kc*32 + quad*8];
      bf16x8 a1 = *(const bf16x8*)&AF[(wm*32 + 16 + l16)*520 + kc*32 + quad*8];
      bf16x8 b0 = *(const bf16x8*)&Wb[(wn*64 +  0 + l16)*40 + quad*8];
      bf16x8 b1 = *(const bf16x8*)&Wb[(wn*64 + 16 + l16)*40 + quad*8];
      bf16x8 b2 = *(const bf16x8*)&Wb[(wn*64 + 32 + l16)*40 + quad*8];
      bf16x8 b3 = *(const bf16x8*)&Wb[(wn*64 + 48 + l16)*40 + quad*8];
      acc[0][0] = MFMA16(a0, b0, acc[0][0]);
      acc[0][1] = MFMA16(a0, b1, acc[0][1]);
      acc[0][2] = MFMA16(a0, b2, acc[0][2]);
      acc[0][3] = MFMA16(a0, b3, acc[0][3]);
      acc[1][0] = MFMA16(a1, b0, acc[1][0]);
      acc[1][1] = MFMA16(a1, b1, acc[1][1]);
      acc[1][2] = MFMA16(a1, b2, acc[1][2]);
      acc[1][3] = MFMA16(a1, b3, acc[1][3]);
    }
    #pragma unroll
    for (int ni = 0; ni < 4; ++ni){
      float bb = bl[nt*128 + wn*64 + ni*16 + l16];
      #pragma unroll
      for (int mi = 0; mi < 2; ++mi){
        float e0 = acc[mi][ni][0] + bb; e0 = e0 > 0.f ? e0 : 0.f;
        float e1 = acc[mi][ni][1] + bb; e1 = e1 > 0.f ? e1 : 0.f;
        float e2 = acc[mi][ni][2] + bb; e2 = e2 > 0.f ? e2 : 0.f;
        float e3 = acc[mi][ni][3] + bb; e3 = e3 > 0.f ? e3 : 0.f;
        pkF[nt][mi*8 + ni*2 + 0] = pkbf(e0, e1);
        pkF[nt][mi*8 + ni*2 + 1] = pkbf(e2, e3);
      }
    }
  }

  // ---- transpose pkF (C-layout) -> F tile in AF (A-operand layout) ----
  __syncthreads();
  #pragma unroll
  for (int nt = 0; nt < 4; ++nt)
    #pragma unroll
    for (int ni = 0; ni < 4; ++ni)
      #pragma unroll
      for (int mi = 0; mi < 2; ++mi){
        int col = nt*128 + wn*64 + ni*16 + l16;
        int r0 = (wm*32 + mi*16 + quad*4)*520 + col;
        uint32_t x = pkF[nt][mi*8 + ni*2], y = pkF[nt][mi*8 + ni*2 + 1];
        AF[r0]        = (u16)x;
        AF[r0 + 520]  = (u16)(x >> 16);
        AF[r0 + 1040] = (u16)y;
        AF[r0 + 1560] = (u16)(y >> 16);
      }

  // ---- stage 2: [Q|V] = f @ W^T ; Q first (nt2=0 -> e), then V weighted ----
  for (int nt2 = 0; nt2 < 5; ++nt2){
    #pragma unroll
    for (int mi = 0; mi < 2; ++mi)
      #pragma unroll
      for (int ni = 0; ni < 4; ++ni) acc[mi][ni] = (f32x4){0.f,0.f,0.f,0.f};
    for (int kc = 0; kc < 16; ++kc, ++ci){
      __syncthreads();
      *(uint4*)wdst = w0; *(uint4*)(wdst + 8) = w1;
      __syncthreads();
      if (ci < 143){
        const u16* sp = chunk_src(wl, wvq, ci + 1, rS, pS);
        w0 = *(const uint4*)sp; w1 = *(const uint4*)(sp + 8);
      }
      bf16x8 a0 = *(const bf16x8*)&AF[(wm*32 + l16)*520 + kc*32 + quad*8];
      bf16x8 a1 = *(const bf16x8*)&AF[(wm*32 + 16 + l16)*520 + kc*32 + quad*8];
      bf16x8 b0 = *(const bf16x8*)&Wb[(wn*64 +  0 + l16)*40 + quad*8];
      bf16x8 b1 = *(const bf16x8*)&Wb[(wn*64 + 16 + l16)*40 + quad*8];
      bf16x8 b2 = *(const bf16x8*)&Wb[(wn*64 + 32 + l16)*40 + quad*8];
      bf16x8 b3 = *(const bf16x8*)&Wb[(wn*64 + 48 + l16)*40 + quad*8];
      acc[0][0] = MFMA16(a0, b0, acc[0][0]);
      acc[0][1] = MFMA16(a0, b1, acc[0][1]);
      acc[0][2] = MFMA16(a0, b2, acc[0][2]);
      acc[0][3] = MFMA16(a0, b3, acc[0][3]);
      acc[1][0] = MFMA16(a1, b0, acc[1][0]);
      acc[1][1] = MFMA16(a1, b1, acc[1][1]);
      acc[1][2] = MFMA16(a1, b2, acc[1][2]);
      acc[1][3] = MFMA16(a1, b3, acc[1][3]);
    }
    if (nt2 == 0){
      // ---- Q epilogue: tanh, dot with qmv, e = exp(score/sqrt(128)) ----
      float p0[2][4], p1[2][4];
      #pragma unroll
      for (int mi = 0; mi < 2; ++mi)
        #pragma unroll
        for (int e = 0; e < 4; ++e){ p0[mi][e] = 0.f; p1[mi][e] = 0.f; }
      #pragma unroll
      for (int ni = 0; ni < 4; ++ni){
        int qc = wn*64 + ni*16 + l16;
        float bqv = bq[qc], q0 = qmv[qc], q1 = qmv[QD + qc];
        #pragma unroll
        for (int mi = 0; mi < 2; ++mi)
          #pragma unroll
          for (int e = 0; e < 4; ++e){
            float tq = tanhf(acc[mi][ni][e] + bqv);
            p0[mi][e] += tq * q0;
            p1[mi][e] += tq * q1;
          }
      }
      #pragma unroll
      for (int off = 1; off <= 8; off <<= 1)
        #pragma unroll
        for (int mi = 0; mi < 2; ++mi)
          #pragma unroll
          for (int e = 0; e < 4; ++e){
            p0[mi][e] += __shfl_xor(p0[mi][e], off);
            p1[mi][e] += __shfl_xor(p1[mi][e], off);
          }
      __syncthreads();   // Wb MFMA reads done before sred overlay write
      if (l16 == 0){
        #pragma unroll
        for (int mi = 0; mi < 2; ++mi)
          #pragma unroll
          for (int e = 0; e < 4; ++e){
            int row = wm*32 + mi*16 + quad*4 + e;
            sred[(row*2 + 0)*2 + wn] = p0[mi][e];
            sred[(row*2 + 1)*2 + wn] = p1[mi][e];
          }
      }
      __syncthreads();
      if (tid < 128){
        int row = tid >> 1, j = tid & 1;
        float sv = (sred[(row*2 + j)*2 + 0] + sred[(row*2 + j)*2 + 1]) * 0.08838834764831845f;
        bool valid = (i0 + row) < NROWS;
        float ev = valid ? __expf(sv) : 0.f;
        Ef[row*2 + j] = ev;
        if (valid) Aout[(i0 + row)*2 + j] = ev;
        float t2 = ev;
        #pragma unroll
        for (int off = 2; off <= 32; off <<= 1) t2 += __shfl_xor(t2, off);
        if (lane < 2) gpartE[(size_t)blockIdx.x*4 + (tid >> 6)*2 + j] = t2;
      }
      __syncthreads();   // Ef visible; sred reads done before next Wb store
    } else {
      // ---- V epilogue: e-weighted column sums -> per-block gpart ----
      float e0[2][4], e1[2][4];
      #pragma unroll
      for (int mi = 0; mi < 2; ++mi)
        #pragma unroll
        for (int e = 0; e < 4; ++e){
          int row = wm*32 + mi*16 + quad*4 + e;
          e0[mi][e] = Ef[row*2 + 0];
          e1[mi][e] = Ef[row*2 + 1];
        }
      #pragma unroll
      for (int ni = 0; ni < 4; ++ni){
        int colv = (nt2 - 1)*128 + wn*64 + ni*16 + l16;
        float bvv = bv[colv];
        float b0 = 0.f, b1 = 0.f;
        #pragma unroll
        for (int mi = 0; mi < 2; ++mi)
          #pragma unroll
          for (int e = 0; e < 4; ++e){
            float v = acc[mi][ni][e] + bvv;
            b0 += v * e0[mi][e];
            b1 += v * e1[mi][e];
          }
        b0 += __shfl_xor(b0, 16); b0 += __shfl_xor(b0, 32);
        b1 += __shfl_xor(b1, 16); b1 += __shfl_xor(b1, 32);
        if (quad == 0){
          gpart[((size_t)blockIdx.x*2 + wm)*1024 + colv]       = b0;
          gpart[((size_t)blockIdx.x*2 + wm)*1024 + 512 + colv] = b1;
        }
      }
    }
  }
}

// ---------- k_red: parallel reduce -> sumEV[1024], sumE[2] ----------
__global__ void k_red(const float* __restrict__ gpart, const float* __restrict__ gpartE,
                      float* __restrict__ sumEV, float* __restrict__ sumE){
  const int t = threadIdx.x;
  if (blockIdx.x == 256){
    __shared__ float r0[256], r1[256];
    float s0 = 0.f, s1 = 0.f;
    for (int i = t; i < NB*2; i += 256){ s0 += gpartE[(size_t)i*2]; s1 += gpartE[(size_t)i*2 + 1]; }
    r0[t] = s0; r1[t] = s1;
    __syncthreads();
    for (int st = 128; st; st >>= 1){
      if (t < st){ r0[t] += r0[t + st]; r1[t] += r1[t + st]; }
      __syncthreads();
    }
    if (t == 0){ sumE[0] = r0[0]; sumE[1] = r1[0]; }
    return;
  }
  __shared__ float4 red[256];
  int col4 = blockIdx.x * 4;
  float4 s = {0.f, 0.f, 0.f, 0.f};
  for (int r = t; r < NB*2; r += 256){
    float4 v = *(const float4*)(gpart + (size_t)r*1024 + col4);
    s.x += v.x; s.y += v.y; s.z += v.z; s.w += v.w;
  }
  red[t] = s;
  __syncthreads();
  for (int st = 128; st; st >>= 1){
    if (t < st){
      float4 o = red[t + st];
      red[t].x += o.x; red[t].y += o.y; red[t].z += o.z; red[t].w += o.w;
    }
    __syncthreads();
  }
  if (t == 0) *(float4*)(sumEV + col4) = red[0];
}

// ---------- k_post: normalize A; compute B and Cout ----------
__global__ void k_post(float* __restrict__ out, const float* __restrict__ sumE,
                       const float* __restrict__ sumEV, const float* __restrict__ Wfcc,
                       const float* __restrict__ bfcc){
  if (blockIdx.x < 782){
    int idx = blockIdx.x*256 + threadIdx.x;
    if (idx < 200000) out[2 + idx] = out[2 + idx] / sumE[idx & 1];
    return;
  }
  __shared__ float red[512];
  int t = threadIdx.x;
  float z0 = sumE[0], z1 = sumE[1];
  float c0 = 0.f, c1 = 0.f;
  for (int e = t; e < 1024; e += 256){
    float bvv = sumEV[e] / ((e >> 9) ? z1 : z0);
    out[200002 + e] = bvv;
    c0 += bvv * Wfcc[e];
    c1 += bvv * Wfcc[1024 + e];
  }
  red[t] = c0; red[256 + t] = c1;
  __syncthreads();
  for (int s = 128; s; s >>= 1){
    if (t < s){ red[t] += red[t + s]; red[256 + t] += red[256 + t + s]; }
    __syncthreads();
  }
  if (t == 0){ out[0] = red[0] + bfcc[0]; out[1] = red[256] + bfcc[1]; }
}

// ---------- launch ----------
extern "C" void kernel_launch(void* const* d_in, const int* in_sizes, int n_in,
                              void* d_out, int out_size, void* d_ws, size_t ws_size,
                              hipStream_t stream){
  (void)in_sizes; (void)n_in; (void)out_size; (void)ws_size;
  const float* feats = (const float*)d_in[0];
  const float* c     = (const float*)d_in[1];
  const float* preds = (const float*)d_in[2];
  const float* W_lin = (const float*)d_in[3];
  const float* b_lin = (const float*)d_in[4];
  const float* W_q   = (const float*)d_in[5];
  const float* b_q   = (const float*)d_in[6];
  const float* W_v   = (const float*)d_in[7];
  const float* b_v   = (const float*)d_in[8];
  const float* W_fcc = (const float*)d_in[9];
  const float* b_fcc = (const float*)d_in[10];
  float* out = (float*)d_out;
  char* ws = (char*)d_ws;

  // ws layout (bytes) — every region fully rewritten each call
  u16*   wl_bf  = (u16*)(ws + 0);            // 524288
  u16*   wvq_bf = (u16*)(ws + 524288);       // 655360   -> 1179648
  Scal*  sc     = (Scal*)(ws + 1179648);     // 64       -> 1179712
  float* qmv    = (float*)(ws + 1179712);    // 1024     -> 1180736
  float* sumE   = (float*)(ws + 1180736);    // 64       -> 1180800
  float* sumEV  = (float*)(ws + 1180800);    // 4096     -> 1184896
  float* gpartE = (float*)(ws + 1184896);    // 1563*4*4 = 25008 (pad 25088) -> 1209984
  float* gpart  = (float*)(ws + 1209984);    // 1563*2*1024*4 = 12804096 -> 14014080

  k_conv <<<2304, 256, 0, stream>>>(W_lin, W_v, W_q, wl_bf, wvq_bf);
  k_prep <<<1, 1024, 0, stream>>>(preds, c, feats, W_lin, b_lin, W_q, b_q, sc, qmv);
  k_fused<<<NB, 256, 0, stream>>>(feats, preds, wl_bf, wvq_bf, b_lin, b_v, b_q,
                                  qmv, sc, gpart, gpartE, out + 2);
  k_red  <<<257, 256, 0, stream>>>(gpart, gpartE, sumEV, sumE);
  k_post <<<783, 256, 0, stream>>>(out, sumE, sumEV, W_fcc, b_fcc);
}